// Round 7
// baseline (93.015 us; speedup 1.0000x reference)
//
#include <hip/hip_runtime.h>
#include <hip/hip_fp16.h>
#include <math.h>

#define NB 16
#define PLEN 1024
#define QLEN 256
#define DIM 256
#define MASKV -10000000.0f

typedef __attribute__((ext_vector_type(8))) short short8;
typedef __attribute__((ext_vector_type(4))) float f32x4;

union u4x16 { unsigned short u[4]; int2 v; };
union u8x16 { unsigned short u[8]; int4 v; };

__device__ inline unsigned short f2bf(float x) {
  unsigned int u = __float_as_uint(x);
  u += 0x7FFF + ((u >> 16) & 1);          // round-to-nearest-even
  return (unsigned short)(u >> 16);
}

// ---------------- k_prep2: one pass over passage/question fp32.
__global__ __launch_bounds__(256) void k_prep2(
    const float* __restrict__ passage, const float* __restrict__ question,
    const float* __restrict__ W,
    unsigned short* __restrict__ Pw, unsigned short* __restrict__ Qb,
    unsigned short* __restrict__ PbT, unsigned short* __restrict__ QbT,
    float* __restrict__ sp, float* __restrict__ sq) {
  int bid = blockIdx.x;
  int t = threadIdx.x;
  __shared__ unsigned short T[64][268];
  int isP = bid < NB * 16;
  int b, r0, R;
  const float* src; unsigned short* cast_out; unsigned short* tdst; float* dots;
  const float* wd; const float* wm;
  if (isP) {
    b = bid >> 4; r0 = (bid & 15) * 64; R = PLEN;
    src = passage + ((size_t)b * PLEN + r0) * DIM;
    cast_out = Pw + ((size_t)b * PLEN + r0) * DIM;
    tdst = PbT + (size_t)b * DIM * PLEN;
    dots = sp + b * PLEN + r0;
    wd = W; wm = W + 2 * DIM;
  } else {
    int bq = bid - NB * 16;
    b = bq >> 2; r0 = (bq & 3) * 64; R = QLEN;
    src = question + ((size_t)b * QLEN + r0) * DIM;
    cast_out = Qb + ((size_t)b * QLEN + r0) * DIM;
    tdst = QbT + (size_t)b * DIM * QLEN;
    dots = sq + b * QLEN + r0;
    wd = W + DIM; wm = nullptr;
  }
  int row = t >> 2, c0 = (t & 3) * 64;
  float s = 0.f;
  for (int i = 0; i < 16; ++i) {
    int d = c0 + i * 4;
    float4 x = *(const float4*)&src[(size_t)row * DIM + d];
    s += x.x * wd[d] + x.y * wd[d + 1] + x.z * wd[d + 2] + x.w * wd[d + 3];
    u4x16 tv;
    tv.u[0] = f2bf(x.x); tv.u[1] = f2bf(x.y); tv.u[2] = f2bf(x.z); tv.u[3] = f2bf(x.w);
    *(int2*)&T[row][d] = tv.v;
    u4x16 ov;
    if (isP) {
      ov.u[0] = f2bf(x.x * wm[d]);     ov.u[1] = f2bf(x.y * wm[d + 1]);
      ov.u[2] = f2bf(x.z * wm[d + 2]); ov.u[3] = f2bf(x.w * wm[d + 3]);
    } else ov = tv;
    *(int2*)&cast_out[(size_t)row * DIM + d] = ov.v;
  }
  s += __shfl_xor(s, 1, 64);
  s += __shfl_xor(s, 2, 64);
  if ((t & 3) == 0) dots[row] = s;
  __syncthreads();
  for (int pc = 0; pc < 8; ++pc) {
    u8x16 o;
    for (int e = 0; e < 8; ++e) o.u[e] = T[pc * 8 + e][t];
    *(int4*)&tdst[(size_t)t * R + r0 + pc * 8] = o.v;
  }
}

// ---------------- k_scoreA (grid NB*32, 512 thr): 32 p-rows x 256 q per block.
// score GEMM + mask + S16 (via LDS, coalesced) + col partials + exact row softmax
// -> P2Q + out1 GEMM.  8 waves = 2 row-strips x 4 q-quarters.
__global__ __launch_bounds__(512) void k_scoreA(
    const unsigned short* __restrict__ Pw, const unsigned short* __restrict__ Qb,
    const unsigned short* __restrict__ QbT,
    const float* __restrict__ sp, const float* __restrict__ sq,
    const int* __restrict__ pmask, const int* __restrict__ qmask,
    const float* __restrict__ bias,
    __half* __restrict__ S16, float* __restrict__ CM, float* __restrict__ CL,
    unsigned short* __restrict__ P2Q, float* __restrict__ out1) {
  int bid = blockIdx.x;
  int b = bid >> 5;
  int tile = bid & 31;
  int p0 = tile * 32;
  int t = threadIdx.x, lane = t & 63, wv = t >> 6;   // 8 waves
  int s = wv >> 2, h = wv & 3;                        // row-strip 0..1 (16 rows), q-quarter 0..3 (64 q)
  __shared__ __align__(16) unsigned short As[32][40];
  __shared__ __align__(16) unsigned short Bs[256][40];
  __shared__ __align__(16) unsigned short Pl[32][264];   // reused: fp16 S staging, then bf16 P
  __shared__ float redM[2][256], redL[2][256];
  __shared__ float rowM[32][4], rowL[32][4];

  // ---- phase 1: score GEMM (32 x 256, K = 256); wave = 16 rows x 64 q
  f32x4 acc[4] = {};
  for (int kt = 0; kt < DIM; kt += 32) {
    __syncthreads();
    for (int i = 0; i < 2; ++i) {
      int idx = t + i * 512;
      int row = idx >> 2, c = (idx & 3) * 8;
      *(int4*)&Bs[row][c] = *(const int4*)&Qb[((size_t)b * QLEN + row) * DIM + kt + c];
    }
    if (t < 128) {
      int row = t >> 2, c = (t & 3) * 8;
      *(int4*)&As[row][c] = *(const int4*)&Pw[((size_t)b * PLEN + p0 + row) * DIM + kt + c];
    }
    __syncthreads();
    short8 af = *(const short8*)&As[s * 16 + (lane & 15)][(lane >> 4) * 8];
    for (int j = 0; j < 4; ++j) {
      short8 bf = *(const short8*)&Bs[h * 64 + j * 16 + (lane & 15)][(lane >> 4) * 8];
      acc[j] = __builtin_amdgcn_mfma_f32_16x16x32_bf16(af, bf, acc[j], 0, 0, 0);
    }
  }

  // ---- phase 2: bias + mask epilogue; stage fp16 S tile in Pl (LDS)
  float b0 = bias[0];
  int prow[4]; float spv[4]; int pmv[4];
  for (int r = 0; r < 4; ++r) {
    prow[r] = p0 + s * 16 + (lane >> 4) * 4 + r;
    spv[r] = sp[b * PLEN + prow[r]] + b0;
    pmv[r] = pmask[b * PLEN + prow[r]];
  }
  float sqv[4]; int qmv[4];
  for (int j = 0; j < 4; ++j) {
    int q = h * 64 + j * 16 + (lane & 15);
    sqv[j] = sq[b * QLEN + q];
    qmv[j] = qmask[b * QLEN + q];
  }
  __syncthreads();   // Pl reuse: everyone done with phase-1 LDS reads
  for (int j = 0; j < 4; ++j) {
    int q = h * 64 + j * 16 + (lane & 15);
    for (int r = 0; r < 4; ++r) {
      float v = acc[j][r] + spv[r] + sqv[j];
      if (pmv[r] | qmv[j]) v = MASKV;
      acc[j][r] = v;
      int rl = s * 16 + (lane >> 4) * 4 + r;
      Pl[rl][q] = __half_as_ushort(__float2half(v));
    }
  }

  // ---- phase 3a: column partials (per strip) + row partials (per quarter)
  for (int j = 0; j < 4; ++j) {
    float m = fmaxf(fmaxf(acc[j][0], acc[j][1]), fmaxf(acc[j][2], acc[j][3]));
    m = fmaxf(m, __shfl_xor(m, 16, 64));
    m = fmaxf(m, __shfl_xor(m, 32, 64));
    float e = 0.f;
    for (int r = 0; r < 4; ++r) e += __expf(acc[j][r] - m);
    e += __shfl_xor(e, 16, 64);
    e += __shfl_xor(e, 32, 64);
    if ((lane >> 4) == 0) {
      redM[s][h * 64 + j * 16 + (lane & 15)] = m;
      redL[s][h * 64 + j * 16 + (lane & 15)] = e;
    }
  }
  for (int r = 0; r < 4; ++r) {
    int rl = s * 16 + (lane >> 4) * 4 + r;
    float m = acc[0][r];
    for (int j = 1; j < 4; ++j) m = fmaxf(m, acc[j][r]);
    for (int msk = 1; msk <= 8; msk <<= 1) m = fmaxf(m, __shfl_xor(m, msk, 64));
    float l = 0.f;
    for (int j = 0; j < 4; ++j) l += __expf(acc[j][r] - m);
    for (int msk = 1; msk <= 8; msk <<= 1) l += __shfl_xor(l, msk, 64);
    if ((lane & 15) == 0) { rowM[rl][h] = m; rowL[rl][h] = l; }
  }
  __syncthreads();

  // ---- S16 copy-out (coalesced, from Pl fp16) — overlaps with 3b
  for (int k = 0; k < 2; ++k) {
    int idx = t + k * 512;
    int row = idx >> 5, c8 = idx & 31;
    *(int4*)&S16[((size_t)b * PLEN + p0 + row) * QLEN + c8 * 8] = *(const int4*)&Pl[row][c8 * 8];
  }

  // ---- phase 3b: CM/CL store (combine 2 strips)
  if (t < 256) {
    int q = t;
    float M = fmaxf(redM[0][q], redM[1][q]);
    float L = redL[0][q] * __expf(redM[0][q] - M) + redL[1][q] * __expf(redM[1][q] - M);
    size_t o = ((size_t)b * 32 + tile) * QLEN + q;
    CM[o] = M; CL[o] = L;
  }
  __syncthreads();   // S16 copy done before Pl overwrite

  // ---- phase 4: exact row softmax (combine 4 quarters) -> Pl (bf16)
  for (int r = 0; r < 4; ++r) {
    int rl = s * 16 + (lane >> 4) * 4 + r;
    float m0 = rowM[rl][0], m1 = rowM[rl][1], m2 = rowM[rl][2], m3 = rowM[rl][3];
    float m = fmaxf(fmaxf(m0, m1), fmaxf(m2, m3));
    float l = rowL[rl][0] * __expf(m0 - m) + rowL[rl][1] * __expf(m1 - m)
            + rowL[rl][2] * __expf(m2 - m) + rowL[rl][3] * __expf(m3 - m);
    float inv = 1.0f / l;
    for (int j = 0; j < 4; ++j) {
      float e = (pmv[r] | qmv[j]) ? 0.0f : __expf(acc[j][r] - m) * inv;
      Pl[rl][h * 64 + j * 16 + (lane & 15)] = f2bf(e);
    }
  }
  __syncthreads();

  // ---- P2Q global store (coalesced from LDS)
  for (int k = 0; k < 2; ++k) {
    int idx = t + k * 512;
    int row = idx >> 5, c8 = idx & 31;
    *(int4*)&P2Q[((size_t)b * PLEN + p0 + row) * QLEN + c8 * 8] = *(const int4*)&Pl[row][c8 * 8];
  }

  // ---- phase 5: out1 = P @ QbT^T  (K = 256); wave = 16 rows x 64 d
  f32x4 acc2[4] = {};
  for (int kt = 0; kt < QLEN; kt += 32) {
    __syncthreads();
    {
      int row = t >> 1, c = (t & 1) * 16;
      *(int4*)&Bs[row][c]     = *(const int4*)&QbT[((size_t)b * DIM + row) * QLEN + kt + c];
      *(int4*)&Bs[row][c + 8] = *(const int4*)&QbT[((size_t)b * DIM + row) * QLEN + kt + c + 8];
    }
    __syncthreads();
    short8 af = *(const short8*)&Pl[s * 16 + (lane & 15)][kt + (lane >> 4) * 8];
    for (int j = 0; j < 4; ++j) {
      short8 bf = *(const short8*)&Bs[h * 64 + j * 16 + (lane & 15)][(lane >> 4) * 8];
      acc2[j] = __builtin_amdgcn_mfma_f32_16x16x32_bf16(af, bf, acc2[j], 0, 0, 0);
    }
  }
  for (int j = 0; j < 4; ++j) {
    int d = h * 64 + j * 16 + (lane & 15);
    for (int r = 0; r < 4; ++r)
      out1[((size_t)b * PLEN + prow[r]) * DIM + d] = acc2[j][r];
  }
}

// ---------------- k_colfinish: W2t[b,q,p] = bf16(exp(S16 - M_q)/L_q); 64q x 64p per block
__global__ __launch_bounds__(256) void k_colfinish(
    const __half* __restrict__ S16,
    const float* __restrict__ CM, const float* __restrict__ CL,
    unsigned short* __restrict__ W2t) {
  int bid = blockIdx.x;
  int b = bid >> 6, qt = (bid >> 4) & 3, pg = bid & 15;
  int q0 = qt * 64, p0 = pg * 64;
  int t = threadIdx.x;
  __shared__ float Mq[64], iLq[64];
  if (t < 64) {
    int q = q0 + t;
    float M = CM[((size_t)b * 32) * QLEN + q];
    for (int tm = 1; tm < 32; ++tm)
      M = fmaxf(M, CM[((size_t)b * 32 + tm) * QLEN + q]);
    float L = 0.f;
    for (int tm = 0; tm < 32; ++tm) {
      size_t o = ((size_t)b * 32 + tm) * QLEN + q;
      L += CL[o] * __expf(CM[o] - M);
    }
    Mq[t] = M; iLq[t] = 1.0f / L;
  }
  __shared__ __align__(16) __half T[64][80];
  for (int k = 0; k < 2; ++k) {
    int idx = t + k * 256;
    int rr = idx >> 3, i4 = idx & 7;
    *(int4*)&T[rr][i4 * 8] =
        *(const int4*)&S16[((size_t)b * PLEN + p0 + rr) * QLEN + q0 + i4 * 8];
  }
  __syncthreads();
  int qq = t >> 2, k4 = t & 3;
  float M = Mq[qq], iL = iLq[qq];
  union { unsigned short u[16]; int4 v[2]; } o;
  for (int e = 0; e < 16; ++e) {
    int pp = k4 * 16 + e;
    float sv = __half2float(T[pp][qq]);
    o.u[e] = f2bf(__expf(sv - M) * iL);
  }
  unsigned short* dst = W2t + ((size_t)b * QLEN + q0 + qq) * PLEN + p0 + k4 * 16;
  *(int4*)dst = o.v[0];
  *(int4*)(dst + 8) = o.v[1];
}

// ---------------- k_gemm_qatt: QATTf[kh][b,d,q] = PbT @ W2t^T over K-half (fp32 partial)
__global__ __launch_bounds__(256) void k_gemm_qatt(
    const unsigned short* __restrict__ PbT, const unsigned short* __restrict__ W2t,
    float* __restrict__ QATTf) {
  int bid = blockIdx.x;
  int kh = bid >> 8;
  int r8 = bid & 255;
  int b = r8 >> 4;
  int tm = (r8 >> 2) & 3;
  int tn = r8 & 3;
  const unsigned short* A  = PbT + ((size_t)b * DIM + tm * 64) * PLEN;
  const unsigned short* Bm = W2t + ((size_t)b * QLEN + tn * 64) * PLEN;
  float* outp = QATTf + (size_t)kh * NB * DIM * QLEN;
  __shared__ __align__(16) unsigned short As[64][72];
  __shared__ __align__(16) unsigned short Bs[64][72];
  int t = threadIdx.x, lane = t & 63, wid = t >> 6;
  int wm = wid >> 1, wn = wid & 1;
  f32x4 acc[2][2] = {};
  int srow = t >> 3, sc = (t & 7) * 8;
  for (int kt = kh * 512; kt < kh * 512 + 512; kt += 64) {
    __syncthreads();
    for (int i = 0; i < 2; ++i) {
      int r = srow + i * 32;
      *(int4*)&As[r][sc] = *(const int4*)&A[(size_t)r * PLEN + kt + sc];
      *(int4*)&Bs[r][sc] = *(const int4*)&Bm[(size_t)r * PLEN + kt + sc];
    }
    __syncthreads();
    for (int kk = 0; kk < 64; kk += 32) {
      short8 af[2], bf[2];
      for (int i = 0; i < 2; ++i)
        af[i] = *(const short8*)&As[wm * 32 + i * 16 + (lane & 15)][kk + (lane >> 4) * 8];
      for (int j = 0; j < 2; ++j)
        bf[j] = *(const short8*)&Bs[wn * 32 + j * 16 + (lane & 15)][kk + (lane >> 4) * 8];
      for (int i = 0; i < 2; ++i)
        for (int j = 0; j < 2; ++j)
          acc[i][j] = __builtin_amdgcn_mfma_f32_16x16x32_bf16(af[i], bf[j], acc[i][j], 0, 0, 0);
    }
  }
  int d0 = tm * 64 + wm * 32, q0 = tn * 64 + wn * 32;
  for (int i = 0; i < 2; ++i)
    for (int r = 0; r < 4; ++r) {
      int d = d0 + i * 16 + (lane >> 4) * 4 + r;
      for (int j = 0; j < 2; ++j) {
        int q = q0 + j * 16 + (lane & 15);
        outp[((size_t)b * DIM + d) * QLEN + q] = acc[i][j][r];
      }
    }
}

// ---------------- k_gemm_final2: out2 = P2Q @ (QATTf0+QATTf1)^T; 64p x 128d per block
__global__ __launch_bounds__(256) void k_gemm_final2(
    const unsigned short* __restrict__ P2Q, const float* __restrict__ QATTf,
    float* __restrict__ out2) {
  int bid = blockIdx.x;
  int b = bid >> 5;
  int t5 = bid & 31;
  int tm = t5 >> 1;            // 16 p-tiles of 64
  int tn = t5 & 1;             // 2 d-tiles of 128
  int p0 = tm * 64, d0 = tn * 128;
  const float* Q0 = QATTf;
  const float* Q1 = QATTf + (size_t)NB * DIM * QLEN;
  __shared__ __align__(16) unsigned short As[64][40];
  __shared__ __align__(16) unsigned short Bc[128][40];
  int t = threadIdx.x, lane = t & 63, wv = t >> 6;   // 4 waves; wave = 16 rows x 128 d
  f32x4 acc[8] = {};
  for (int kt = 0; kt < QLEN; kt += 32) {
    __syncthreads();
    {
      int row = t >> 2, c = (t & 3) * 8;
      *(int4*)&As[row][c] = *(const int4*)&P2Q[((size_t)b * PLEN + p0 + row) * QLEN + kt + c];
    }
    for (int k = 0; k < 2; ++k) {
      int pos = t + k * 256;
      int row = pos >> 2, c = (pos & 3) * 8;
      const float* s0 = Q0 + ((size_t)b * DIM + d0 + row) * QLEN + kt + c;
      const float* s1 = Q1 + ((size_t)b * DIM + d0 + row) * QLEN + kt + c;
      float4 a0 = *(const float4*)s0, a1 = *(const float4*)(s0 + 4);
      float4 b0v = *(const float4*)s1, b1v = *(const float4*)(s1 + 4);
      u8x16 o;
      o.u[0] = f2bf(a0.x + b0v.x); o.u[1] = f2bf(a0.y + b0v.y);
      o.u[2] = f2bf(a0.z + b0v.z); o.u[3] = f2bf(a0.w + b0v.w);
      o.u[4] = f2bf(a1.x + b1v.x); o.u[5] = f2bf(a1.y + b1v.y);
      o.u[6] = f2bf(a1.z + b1v.z); o.u[7] = f2bf(a1.w + b1v.w);
      *(int4*)&Bc[row][c] = o.v;
    }
    __syncthreads();
    short8 af = *(const short8*)&As[wv * 16 + (lane & 15)][(lane >> 4) * 8];
    for (int j = 0; j < 8; ++j) {
      short8 bf = *(const short8*)&Bc[j * 16 + (lane & 15)][(lane >> 4) * 8];
      acc[j] = __builtin_amdgcn_mfma_f32_16x16x32_bf16(af, bf, acc[j], 0, 0, 0);
    }
  }
  for (int j = 0; j < 8; ++j) {
    int d = d0 + j * 16 + (lane & 15);
    for (int r = 0; r < 4; ++r) {
      int p = p0 + wv * 16 + (lane >> 4) * 4 + r;
      out2[((size_t)b * PLEN + p) * DIM + d] = acc[j][r];
    }
  }
}

extern "C" void kernel_launch(void* const* d_in, const int* in_sizes, int n_in,
                              void* d_out, int out_size, void* d_ws, size_t ws_size,
                              hipStream_t stream) {
  const float* passage  = (const float*)d_in[0];
  const float* question = (const float*)d_in[1];
  const int*   pmask    = (const int*)d_in[2];
  const int*   qmask    = (const int*)d_in[3];
  const float* W        = (const float*)d_in[4];
  const float* bias     = (const float*)d_in[5];
  float* out = (float*)d_out;

  const size_t NS = (size_t)NB * PLEN * QLEN;    // 4,194,304
  const size_t NQ = (size_t)NB * QLEN * DIM;     // 1,048,576
  char* w = (char*)d_ws;
  __half* S16 = (__half*)w;                  w += NS * 2;
  unsigned short* Pw   = (unsigned short*)w; w += NS * 2;
  unsigned short* Qb   = (unsigned short*)w; w += NQ * 2;
  unsigned short* PbT  = (unsigned short*)w; w += NS * 2;
  unsigned short* QbT  = (unsigned short*)w; w += NQ * 2;
  unsigned short* P2Q  = (unsigned short*)w; w += NS * 2;
  unsigned short* W2t  = (unsigned short*)w; w += NS * 2;
  float* QATTf = (float*)w;                  w += 2 * NQ * 4;   // two fp32 K-halves
  float* CM = (float*)w;                     w += (size_t)NB * 32 * QLEN * 4;
  float* CL = (float*)w;                     w += (size_t)NB * 32 * QLEN * 4;
  float* sp = (float*)w;                     w += (size_t)NB * PLEN * 4;
  float* sq = (float*)w;

  float* out1 = out;
  float* out2 = out + (size_t)NB * PLEN * DIM;

  k_prep2<<<dim3(NB * 16 + NB * 4), dim3(256), 0, stream>>>(
      passage, question, W, Pw, Qb, PbT, QbT, sp, sq);
  k_scoreA<<<dim3(NB * 32), dim3(512), 0, stream>>>(
      Pw, Qb, QbT, sp, sq, pmask, qmask, bias, S16, CM, CL, P2Q, out1);
  k_colfinish<<<dim3(NB * 4 * 16), dim3(256), 0, stream>>>(
      S16, CM, CL, W2t);
  k_gemm_qatt<<<dim3(2 * NB * 16), dim3(256), 0, stream>>>(
      PbT, W2t, QATTf);
  k_gemm_final2<<<dim3(NB * 16 * 2), dim3(256), 0, stream>>>(
      P2Q, QATTf, out2);
}

// Round 8
// 80.411 us; speedup vs baseline: 1.1567x; 1.1567x over previous
//
#include <hip/hip_runtime.h>
#include <hip/hip_fp16.h>
#include <math.h>

#define NB 16
#define PLEN 1024
#define QLEN 256
#define DIM 256
#define MASKV -10000000.0f

typedef __attribute__((ext_vector_type(8))) short short8;
typedef __attribute__((ext_vector_type(4))) float f32x4;

union u4x16 { unsigned short u[4]; int2 v; };
union u8x16 { unsigned short u[8]; int4 v; };

__device__ inline unsigned short f2bf(float x) {
  unsigned int u = __float_as_uint(x);
  u += 0x7FFF + ((u >> 16) & 1);          // round-to-nearest-even
  return (unsigned short)(u >> 16);
}

// ---------------- k_prep2: one pass over passage/question fp32.
__global__ __launch_bounds__(256) void k_prep2(
    const float* __restrict__ passage, const float* __restrict__ question,
    const float* __restrict__ W,
    unsigned short* __restrict__ Pw, unsigned short* __restrict__ Qb,
    unsigned short* __restrict__ PbT, unsigned short* __restrict__ QbT,
    float* __restrict__ sp, float* __restrict__ sq) {
  int bid = blockIdx.x;
  int t = threadIdx.x;
  __shared__ unsigned short T[64][268];
  int isP = bid < NB * 16;
  int b, r0, R;
  const float* src; unsigned short* cast_out; unsigned short* tdst; float* dots;
  const float* wd; const float* wm;
  if (isP) {
    b = bid >> 4; r0 = (bid & 15) * 64; R = PLEN;
    src = passage + ((size_t)b * PLEN + r0) * DIM;
    cast_out = Pw + ((size_t)b * PLEN + r0) * DIM;
    tdst = PbT + (size_t)b * DIM * PLEN;
    dots = sp + b * PLEN + r0;
    wd = W; wm = W + 2 * DIM;
  } else {
    int bq = bid - NB * 16;
    b = bq >> 2; r0 = (bq & 3) * 64; R = QLEN;
    src = question + ((size_t)b * QLEN + r0) * DIM;
    cast_out = Qb + ((size_t)b * QLEN + r0) * DIM;
    tdst = QbT + (size_t)b * DIM * QLEN;
    dots = sq + b * QLEN + r0;
    wd = W + DIM; wm = nullptr;
  }
  int row = t >> 2, c0 = (t & 3) * 64;
  float s = 0.f;
  for (int i = 0; i < 16; ++i) {
    int d = c0 + i * 4;
    float4 x = *(const float4*)&src[(size_t)row * DIM + d];
    s += x.x * wd[d] + x.y * wd[d + 1] + x.z * wd[d + 2] + x.w * wd[d + 3];
    u4x16 tv;
    tv.u[0] = f2bf(x.x); tv.u[1] = f2bf(x.y); tv.u[2] = f2bf(x.z); tv.u[3] = f2bf(x.w);
    *(int2*)&T[row][d] = tv.v;
    u4x16 ov;
    if (isP) {
      ov.u[0] = f2bf(x.x * wm[d]);     ov.u[1] = f2bf(x.y * wm[d + 1]);
      ov.u[2] = f2bf(x.z * wm[d + 2]); ov.u[3] = f2bf(x.w * wm[d + 3]);
    } else ov = tv;
    *(int2*)&cast_out[(size_t)row * DIM + d] = ov.v;
  }
  s += __shfl_xor(s, 1, 64);
  s += __shfl_xor(s, 2, 64);
  if ((t & 3) == 0) dots[row] = s;
  __syncthreads();
  for (int pc = 0; pc < 8; ++pc) {
    u8x16 o;
    for (int e = 0; e < 8; ++e) o.u[e] = T[pc * 8 + e][t];
    *(int4*)&tdst[(size_t)t * R + r0 + pc * 8] = o.v;
  }
}

// ---------------- k_scoreA (grid NB*16, 512 thr): 64 p-rows x 256 q per block.
// T14 double-buffered staging in both GEMM phases; 1 barrier per K-step.
// 8 waves = 4 row-strips x 2 q-halves.
__global__ __launch_bounds__(512) void k_scoreA(
    const unsigned short* __restrict__ Pw, const unsigned short* __restrict__ Qb,
    const unsigned short* __restrict__ QbT,
    const float* __restrict__ sp, const float* __restrict__ sq,
    const int* __restrict__ pmask, const int* __restrict__ qmask,
    const float* __restrict__ bias,
    __half* __restrict__ S16, float* __restrict__ CM, float* __restrict__ CL,
    unsigned short* __restrict__ P2Q, float* __restrict__ out1) {
  int bid = blockIdx.x;
  int b = bid >> 4;
  int tile = bid & 15;
  int p0 = tile * 64;
  int t = threadIdx.x, lane = t & 63, wv = t >> 6;   // 8 waves
  int s = wv >> 1, h = wv & 1;                        // strip 0..3 (16 rows), half 0..1 (128 q)
  __shared__ __align__(16) unsigned short As[2][64][40];
  __shared__ __align__(16) unsigned short Bs[2][256][40];
  __shared__ __align__(16) unsigned short Pl[64][264];   // fp16 S staging, then bf16 P
  __shared__ float redM[4][256], redL[4][256];
  __shared__ float rowM[64][2], rowL[64][2];

  // staging mapping (per 32-wide K slice)
  int rb = t >> 1, cb = (t & 1) * 16;     // Bs: 256 rows x 32
  int ar = t >> 3, ac = (t & 7) * 4;      // As: 64 rows x 32

  // ---- phase 1: score GEMM (64 x 256, K = 256), dbuf
  f32x4 acc[8] = {};
  int4 rb0, rb1; int2 ra;
  {
    const unsigned short* qsrc = &Qb[((size_t)b * QLEN + rb) * DIM + cb];
    rb0 = *(const int4*)qsrc; rb1 = *(const int4*)(qsrc + 8);
    ra = *(const int2*)&Pw[((size_t)b * PLEN + p0 + ar) * DIM + ac];
  }
  *(int4*)&Bs[0][rb][cb] = rb0;
  *(int4*)&Bs[0][rb][cb + 8] = rb1;
  *(int2*)&As[0][ar][ac] = ra;
  __syncthreads();
  int cur = 0;
  for (int ki = 0; ki < 8; ++ki) {
    if (ki < 7) {
      int kt = (ki + 1) * 32;
      const unsigned short* qsrc = &Qb[((size_t)b * QLEN + rb) * DIM + kt + cb];
      rb0 = *(const int4*)qsrc; rb1 = *(const int4*)(qsrc + 8);
      ra = *(const int2*)&Pw[((size_t)b * PLEN + p0 + ar) * DIM + kt + ac];
    }
    short8 af = *(const short8*)&As[cur][s * 16 + (lane & 15)][(lane >> 4) * 8];
    for (int j = 0; j < 8; ++j) {
      short8 bf = *(const short8*)&Bs[cur][h * 128 + j * 16 + (lane & 15)][(lane >> 4) * 8];
      acc[j] = __builtin_amdgcn_mfma_f32_16x16x32_bf16(af, bf, acc[j], 0, 0, 0);
    }
    if (ki < 7) {
      int nxt = cur ^ 1;
      *(int4*)&Bs[nxt][rb][cb] = rb0;
      *(int4*)&Bs[nxt][rb][cb + 8] = rb1;
      *(int2*)&As[nxt][ar][ac] = ra;
      cur = nxt;
    }
    __syncthreads();
  }

  // ---- phase 2: bias + mask epilogue; stage fp16 S tile in Pl
  float b0 = bias[0];
  int prow[4]; float spv[4]; int pmv[4];
  for (int r = 0; r < 4; ++r) {
    prow[r] = p0 + s * 16 + (lane >> 4) * 4 + r;
    spv[r] = sp[b * PLEN + prow[r]] + b0;
    pmv[r] = pmask[b * PLEN + prow[r]];
  }
  float sqv[8]; int qmv[8];
  for (int j = 0; j < 8; ++j) {
    int q = h * 128 + j * 16 + (lane & 15);
    sqv[j] = sq[b * QLEN + q];
    qmv[j] = qmask[b * QLEN + q];
  }
  for (int j = 0; j < 8; ++j) {
    int q = h * 128 + j * 16 + (lane & 15);
    for (int r = 0; r < 4; ++r) {
      float v = acc[j][r] + spv[r] + sqv[j];
      if (pmv[r] | qmv[j]) v = MASKV;
      acc[j][r] = v;
      int rl = s * 16 + (lane >> 4) * 4 + r;
      Pl[rl][q] = __half_as_ushort(__float2half(v));
    }
  }

  // ---- phase 3a: column partials (per strip) + row partials (per half)
  for (int j = 0; j < 8; ++j) {
    float m = fmaxf(fmaxf(acc[j][0], acc[j][1]), fmaxf(acc[j][2], acc[j][3]));
    m = fmaxf(m, __shfl_xor(m, 16, 64));
    m = fmaxf(m, __shfl_xor(m, 32, 64));
    float e = 0.f;
    for (int r = 0; r < 4; ++r) e += __expf(acc[j][r] - m);
    e += __shfl_xor(e, 16, 64);
    e += __shfl_xor(e, 32, 64);
    if ((lane >> 4) == 0) {
      redM[s][h * 128 + j * 16 + (lane & 15)] = m;
      redL[s][h * 128 + j * 16 + (lane & 15)] = e;
    }
  }
  for (int r = 0; r < 4; ++r) {
    int rl = s * 16 + (lane >> 4) * 4 + r;
    float m = acc[0][r];
    for (int j = 1; j < 8; ++j) m = fmaxf(m, acc[j][r]);
    for (int msk = 1; msk <= 8; msk <<= 1) m = fmaxf(m, __shfl_xor(m, msk, 64));
    float l = 0.f;
    for (int j = 0; j < 8; ++j) l += __expf(acc[j][r] - m);
    for (int msk = 1; msk <= 8; msk <<= 1) l += __shfl_xor(l, msk, 64);
    if ((lane & 15) == 0) { rowM[rl][h] = m; rowL[rl][h] = l; }
  }
  __syncthreads();

  // ---- S16 copy-out (coalesced from Pl)
  for (int k = 0; k < 4; ++k) {
    int idx = t + k * 512;
    int row = idx >> 5, c8 = idx & 31;
    *(int4*)&S16[((size_t)b * PLEN + p0 + row) * QLEN + c8 * 8] = *(const int4*)&Pl[row][c8 * 8];
  }

  // ---- phase 3b: CM/CL store (combine 4 strips)
  if (t < 256) {
    int q = t;
    float M = fmaxf(fmaxf(redM[0][q], redM[1][q]), fmaxf(redM[2][q], redM[3][q]));
    float L = redL[0][q] * __expf(redM[0][q] - M) + redL[1][q] * __expf(redM[1][q] - M)
            + redL[2][q] * __expf(redM[2][q] - M) + redL[3][q] * __expf(redM[3][q] - M);
    size_t o = ((size_t)b * 16 + tile) * QLEN + q;
    CM[o] = M; CL[o] = L;
  }
  __syncthreads();   // S16 copy done before Pl overwrite

  // ---- phase 4: exact row softmax (combine 2 halves) -> Pl (bf16)
  for (int r = 0; r < 4; ++r) {
    int rl = s * 16 + (lane >> 4) * 4 + r;
    float m0 = rowM[rl][0], m1 = rowM[rl][1];
    float m = fmaxf(m0, m1);
    float l = rowL[rl][0] * __expf(m0 - m) + rowL[rl][1] * __expf(m1 - m);
    float inv = 1.0f / l;
    for (int j = 0; j < 8; ++j) {
      float e = (pmv[r] | qmv[j]) ? 0.0f : __expf(acc[j][r] - m) * inv;
      Pl[rl][h * 128 + j * 16 + (lane & 15)] = f2bf(e);
    }
  }
  __syncthreads();

  // ---- P2Q global store (coalesced from Pl)
  for (int k = 0; k < 4; ++k) {
    int idx = t + k * 512;
    int row = idx >> 5, c8 = idx & 31;
    *(int4*)&P2Q[((size_t)b * PLEN + p0 + row) * QLEN + c8 * 8] = *(const int4*)&Pl[row][c8 * 8];
  }

  // ---- phase 5: out1 = P @ QbT^T (K = 256), dbuf over QbT
  f32x4 acc2[8] = {};
  {
    const unsigned short* qsrc = &QbT[((size_t)b * DIM + rb) * QLEN + cb];
    rb0 = *(const int4*)qsrc; rb1 = *(const int4*)(qsrc + 8);
  }
  *(int4*)&Bs[0][rb][cb] = rb0;
  *(int4*)&Bs[0][rb][cb + 8] = rb1;
  __syncthreads();
  cur = 0;
  for (int ki = 0; ki < 8; ++ki) {
    if (ki < 7) {
      int kt = (ki + 1) * 32;
      const unsigned short* qsrc = &QbT[((size_t)b * DIM + rb) * QLEN + kt + cb];
      rb0 = *(const int4*)qsrc; rb1 = *(const int4*)(qsrc + 8);
    }
    short8 af = *(const short8*)&Pl[s * 16 + (lane & 15)][ki * 32 + (lane >> 4) * 8];
    for (int j = 0; j < 8; ++j) {
      short8 bf = *(const short8*)&Bs[cur][h * 128 + j * 16 + (lane & 15)][(lane >> 4) * 8];
      acc2[j] = __builtin_amdgcn_mfma_f32_16x16x32_bf16(af, bf, acc2[j], 0, 0, 0);
    }
    if (ki < 7) {
      int nxt = cur ^ 1;
      *(int4*)&Bs[nxt][rb][cb] = rb0;
      *(int4*)&Bs[nxt][rb][cb + 8] = rb1;
      cur = nxt;
    }
    __syncthreads();
  }
  for (int j = 0; j < 8; ++j) {
    int d = h * 128 + j * 16 + (lane & 15);
    for (int r = 0; r < 4; ++r)
      out1[((size_t)b * PLEN + prow[r]) * DIM + d] = acc2[j][r];
  }
}

// ---------------- k_colfinish: W2t[b,q,p] = bf16(exp(S16 - M_q)/L_q); 64q x 64p per block
__global__ __launch_bounds__(256) void k_colfinish(
    const __half* __restrict__ S16,
    const float* __restrict__ CM, const float* __restrict__ CL,
    unsigned short* __restrict__ W2t) {
  int bid = blockIdx.x;
  int b = bid >> 6, qt = (bid >> 4) & 3, pg = bid & 15;
  int q0 = qt * 64, p0 = pg * 64;
  int t = threadIdx.x;
  __shared__ float Mq[64], iLq[64];
  if (t < 64) {
    int q = q0 + t;
    float M = CM[((size_t)b * 16) * QLEN + q];
    for (int tm = 1; tm < 16; ++tm)
      M = fmaxf(M, CM[((size_t)b * 16 + tm) * QLEN + q]);
    float L = 0.f;
    for (int tm = 0; tm < 16; ++tm) {
      size_t o = ((size_t)b * 16 + tm) * QLEN + q;
      L += CL[o] * __expf(CM[o] - M);
    }
    Mq[t] = M; iLq[t] = 1.0f / L;
  }
  __shared__ __align__(16) __half T[64][80];
  for (int k = 0; k < 2; ++k) {
    int idx = t + k * 256;
    int rr = idx >> 3, i4 = idx & 7;
    *(int4*)&T[rr][i4 * 8] =
        *(const int4*)&S16[((size_t)b * PLEN + p0 + rr) * QLEN + q0 + i4 * 8];
  }
  __syncthreads();
  int qq = t >> 2, k4 = t & 3;
  float M = Mq[qq], iL = iLq[qq];
  union { unsigned short u[16]; int4 v[2]; } o;
  for (int e = 0; e < 16; ++e) {
    int pp = k4 * 16 + e;
    float sv = __half2float(T[pp][qq]);
    o.u[e] = f2bf(__expf(sv - M) * iL);
  }
  unsigned short* dst = W2t + ((size_t)b * QLEN + q0 + qq) * PLEN + p0 + k4 * 16;
  *(int4*)dst = o.v[0];
  *(int4*)(dst + 8) = o.v[1];
}

// ---------------- k_gemm_qatt: QATTt[b,d,q] = PbT @ W2t^T (K = PLEN), bf16 out, dbuf
__global__ __launch_bounds__(256) void k_gemm_qatt(
    const unsigned short* __restrict__ PbT, const unsigned short* __restrict__ W2t,
    unsigned short* __restrict__ QATTt) {
  int bid = blockIdx.x;
  int b = bid >> 4;
  int tm = (bid >> 2) & 3;
  int tn = bid & 3;
  const unsigned short* A  = PbT + ((size_t)b * DIM + tm * 64) * PLEN;
  const unsigned short* Bm = W2t + ((size_t)b * QLEN + tn * 64) * PLEN;
  __shared__ __align__(16) unsigned short As[2][64][72];
  __shared__ __align__(16) unsigned short Bs[2][64][72];
  int t = threadIdx.x, lane = t & 63, wid = t >> 6;
  int wm = wid >> 1, wn = wid & 1;
  f32x4 acc[2][2] = {};
  int r = t >> 2, g = (t & 3) * 16;
  int4 ra0, ra1, rbb0, rbb1;
  ra0 = *(const int4*)&A[(size_t)r * PLEN + g];
  ra1 = *(const int4*)&A[(size_t)r * PLEN + g + 8];
  rbb0 = *(const int4*)&Bm[(size_t)r * PLEN + g];
  rbb1 = *(const int4*)&Bm[(size_t)r * PLEN + g + 8];
  *(int4*)&As[0][r][g] = ra0; *(int4*)&As[0][r][g + 8] = ra1;
  *(int4*)&Bs[0][r][g] = rbb0; *(int4*)&Bs[0][r][g + 8] = rbb1;
  __syncthreads();
  int cur = 0;
  for (int ki = 0; ki < 16; ++ki) {
    if (ki < 15) {
      int kt = (ki + 1) * 64;
      ra0 = *(const int4*)&A[(size_t)r * PLEN + kt + g];
      ra1 = *(const int4*)&A[(size_t)r * PLEN + kt + g + 8];
      rbb0 = *(const int4*)&Bm[(size_t)r * PLEN + kt + g];
      rbb1 = *(const int4*)&Bm[(size_t)r * PLEN + kt + g + 8];
    }
    for (int kk = 0; kk < 64; kk += 32) {
      short8 af[2], bf[2];
      for (int i = 0; i < 2; ++i)
        af[i] = *(const short8*)&As[cur][wm * 32 + i * 16 + (lane & 15)][kk + (lane >> 4) * 8];
      for (int j = 0; j < 2; ++j)
        bf[j] = *(const short8*)&Bs[cur][wn * 32 + j * 16 + (lane & 15)][kk + (lane >> 4) * 8];
      for (int i = 0; i < 2; ++i)
        for (int j = 0; j < 2; ++j)
          acc[i][j] = __builtin_amdgcn_mfma_f32_16x16x32_bf16(af[i], bf[j], acc[i][j], 0, 0, 0);
    }
    if (ki < 15) {
      int nxt = cur ^ 1;
      *(int4*)&As[nxt][r][g] = ra0; *(int4*)&As[nxt][r][g + 8] = ra1;
      *(int4*)&Bs[nxt][r][g] = rbb0; *(int4*)&Bs[nxt][r][g + 8] = rbb1;
      cur = nxt;
    }
    __syncthreads();
  }
  int d0 = tm * 64 + wm * 32, q0 = tn * 64 + wn * 32;
  for (int i = 0; i < 2; ++i)
    for (int rr = 0; rr < 4; ++rr) {
      int d = d0 + i * 16 + (lane >> 4) * 4 + rr;
      for (int j = 0; j < 2; ++j) {
        int q = q0 + j * 16 + (lane & 15);
        QATTt[((size_t)b * DIM + d) * QLEN + q] = f2bf(acc[i][j][rr]);
      }
    }
}

// ---------------- k_gemm_final2: out2 = P2Q @ QATTt^T; 128p x 128d per block, dbuf
__global__ __launch_bounds__(256) void k_gemm_final2(
    const unsigned short* __restrict__ P2Q, const unsigned short* __restrict__ QATTt,
    float* __restrict__ out2) {
  int bid = blockIdx.x;
  int b = bid >> 4;
  int tm = (bid >> 1) & 7;
  int tn = bid & 1;
  const unsigned short* A  = P2Q + ((size_t)b * PLEN + tm * 128) * QLEN;
  const unsigned short* B2 = QATTt + ((size_t)b * DIM + tn * 128) * QLEN;
  __shared__ __align__(16) unsigned short As[2][128][40];
  __shared__ __align__(16) unsigned short Bc[2][128][40];
  int t = threadIdx.x, lane = t & 63, wid = t >> 6;
  int wm = wid >> 1, wn = wid & 1;
  f32x4 acc[4][4] = {};
  int r = t >> 1, c = (t & 1) * 16;
  int4 ra0, ra1, rbb0, rbb1;
  ra0 = *(const int4*)&A[(size_t)r * QLEN + c];
  ra1 = *(const int4*)&A[(size_t)r * QLEN + c + 8];
  rbb0 = *(const int4*)&B2[(size_t)r * QLEN + c];
  rbb1 = *(const int4*)&B2[(size_t)r * QLEN + c + 8];
  *(int4*)&As[0][r][c] = ra0; *(int4*)&As[0][r][c + 8] = ra1;
  *(int4*)&Bc[0][r][c] = rbb0; *(int4*)&Bc[0][r][c + 8] = rbb1;
  __syncthreads();
  int cur = 0;
  for (int ki = 0; ki < 8; ++ki) {
    if (ki < 7) {
      int kt = (ki + 1) * 32;
      ra0 = *(const int4*)&A[(size_t)r * QLEN + kt + c];
      ra1 = *(const int4*)&A[(size_t)r * QLEN + kt + c + 8];
      rbb0 = *(const int4*)&B2[(size_t)r * QLEN + kt + c];
      rbb1 = *(const int4*)&B2[(size_t)r * QLEN + kt + c + 8];
    }
    short8 af[4], bc[4];
    for (int i = 0; i < 4; ++i)
      af[i] = *(const short8*)&As[cur][wm * 64 + i * 16 + (lane & 15)][(lane >> 4) * 8];
    for (int j = 0; j < 4; ++j)
      bc[j] = *(const short8*)&Bc[cur][wn * 64 + j * 16 + (lane & 15)][(lane >> 4) * 8];
    for (int i = 0; i < 4; ++i)
      for (int j = 0; j < 4; ++j)
        acc[i][j] = __builtin_amdgcn_mfma_f32_16x16x32_bf16(af[i], bc[j], acc[i][j], 0, 0, 0);
    if (ki < 7) {
      int nxt = cur ^ 1;
      *(int4*)&As[nxt][r][c] = ra0; *(int4*)&As[nxt][r][c + 8] = ra1;
      *(int4*)&Bc[nxt][r][c] = rbb0; *(int4*)&Bc[nxt][r][c + 8] = rbb1;
      cur = nxt;
    }
    __syncthreads();
  }
  int p0 = tm * 128 + wm * 64, d0 = tn * 128 + wn * 64;
  for (int i = 0; i < 4; ++i)
    for (int rr = 0; rr < 4; ++rr) {
      int p = p0 + i * 16 + (lane >> 4) * 4 + rr;
      size_t rowo = ((size_t)b * PLEN + p) * DIM;
      for (int j = 0; j < 4; ++j) {
        int d = d0 + j * 16 + (lane & 15);
        out2[rowo + d] = acc[i][j][rr];
      }
    }
}

extern "C" void kernel_launch(void* const* d_in, const int* in_sizes, int n_in,
                              void* d_out, int out_size, void* d_ws, size_t ws_size,
                              hipStream_t stream) {
  const float* passage  = (const float*)d_in[0];
  const float* question = (const float*)d_in[1];
  const int*   pmask    = (const int*)d_in[2];
  const int*   qmask    = (const int*)d_in[3];
  const float* W        = (const float*)d_in[4];
  const float* bias     = (const float*)d_in[5];
  float* out = (float*)d_out;

  const size_t NS = (size_t)NB * PLEN * QLEN;    // 4,194,304
  const size_t NQ = (size_t)NB * QLEN * DIM;     // 1,048,576
  char* w = (char*)d_ws;
  __half* S16 = (__half*)w;                  w += NS * 2;
  unsigned short* Pw   = (unsigned short*)w; w += NS * 2;
  unsigned short* Qb   = (unsigned short*)w; w += NQ * 2;
  unsigned short* PbT  = (unsigned short*)w; w += NS * 2;
  unsigned short* QbT  = (unsigned short*)w; w += NQ * 2;
  unsigned short* P2Q  = (unsigned short*)w; w += NS * 2;
  unsigned short* W2t  = (unsigned short*)w; w += NS * 2;
  unsigned short* QATTt = (unsigned short*)w; w += NQ * 2;
  float* CM = (float*)w;                     w += (size_t)NB * 16 * QLEN * 4;
  float* CL = (float*)w;                     w += (size_t)NB * 16 * QLEN * 4;
  float* sp = (float*)w;                     w += (size_t)NB * PLEN * 4;
  float* sq = (float*)w;

  float* out1 = out;
  float* out2 = out + (size_t)NB * PLEN * DIM;

  k_prep2<<<dim3(NB * 16 + NB * 4), dim3(256), 0, stream>>>(
      passage, question, W, Pw, Qb, PbT, QbT, sp, sq);
  k_scoreA<<<dim3(NB * 16), dim3(512), 0, stream>>>(
      Pw, Qb, QbT, sp, sq, pmask, qmask, bias, S16, CM, CL, P2Q, out1);
  k_colfinish<<<dim3(NB * 64), dim3(256), 0, stream>>>(
      S16, CM, CL, W2t);
  k_gemm_qatt<<<dim3(NB * 16), dim3(256), 0, stream>>>(
      PbT, W2t, QATTt);
  k_gemm_final2<<<dim3(NB * 16), dim3(256), 0, stream>>>(
      P2Q, QATTt, out2);
}

// Round 9
// 79.317 us; speedup vs baseline: 1.1727x; 1.0138x over previous
//
#include <hip/hip_runtime.h>
#include <hip/hip_fp16.h>
#include <math.h>

#define NB 16
#define PLEN 1024
#define QLEN 256
#define DIM 256
#define MASKV -10000000.0f

typedef __attribute__((ext_vector_type(8))) short short8;
typedef __attribute__((ext_vector_type(4))) float f32x4;

union u4x16 { unsigned short u[4]; int2 v; };
union u8x16 { unsigned short u[8]; int4 v; };

__device__ inline unsigned short f2bf(float x) {
  unsigned int u = __float_as_uint(x);
  u += 0x7FFF + ((u >> 16) & 1);          // round-to-nearest-even
  return (unsigned short)(u >> 16);
}

// ---------------- k_prep2: one pass over passage/question fp32.
__global__ __launch_bounds__(256) void k_prep2(
    const float* __restrict__ passage, const float* __restrict__ question,
    const float* __restrict__ W,
    unsigned short* __restrict__ Pw, unsigned short* __restrict__ Qb,
    unsigned short* __restrict__ PbT, unsigned short* __restrict__ QbT,
    float* __restrict__ sp, float* __restrict__ sq) {
  int bid = blockIdx.x;
  int t = threadIdx.x;
  __shared__ unsigned short T[64][268];
  int isP = bid < NB * 16;
  int b, r0, R;
  const float* src; unsigned short* cast_out; unsigned short* tdst; float* dots;
  const float* wd; const float* wm;
  if (isP) {
    b = bid >> 4; r0 = (bid & 15) * 64; R = PLEN;
    src = passage + ((size_t)b * PLEN + r0) * DIM;
    cast_out = Pw + ((size_t)b * PLEN + r0) * DIM;
    tdst = PbT + (size_t)b * DIM * PLEN;
    dots = sp + b * PLEN + r0;
    wd = W; wm = W + 2 * DIM;
  } else {
    int bq = bid - NB * 16;
    b = bq >> 2; r0 = (bq & 3) * 64; R = QLEN;
    src = question + ((size_t)b * QLEN + r0) * DIM;
    cast_out = Qb + ((size_t)b * QLEN + r0) * DIM;
    tdst = QbT + (size_t)b * DIM * QLEN;
    dots = sq + b * QLEN + r0;
    wd = W + DIM; wm = nullptr;
  }
  int row = t >> 2, c0 = (t & 3) * 64;
  float s = 0.f;
  for (int i = 0; i < 16; ++i) {
    int d = c0 + i * 4;
    float4 x = *(const float4*)&src[(size_t)row * DIM + d];
    s += x.x * wd[d] + x.y * wd[d + 1] + x.z * wd[d + 2] + x.w * wd[d + 3];
    u4x16 tv;
    tv.u[0] = f2bf(x.x); tv.u[1] = f2bf(x.y); tv.u[2] = f2bf(x.z); tv.u[3] = f2bf(x.w);
    *(int2*)&T[row][d] = tv.v;
    u4x16 ov;
    if (isP) {
      ov.u[0] = f2bf(x.x * wm[d]);     ov.u[1] = f2bf(x.y * wm[d + 1]);
      ov.u[2] = f2bf(x.z * wm[d + 2]); ov.u[3] = f2bf(x.w * wm[d + 3]);
    } else ov = tv;
    *(int2*)&cast_out[(size_t)row * DIM + d] = ov.v;
  }
  s += __shfl_xor(s, 1, 64);
  s += __shfl_xor(s, 2, 64);
  if ((t & 3) == 0) dots[row] = s;
  __syncthreads();
  for (int pc = 0; pc < 8; ++pc) {
    u8x16 o;
    for (int e = 0; e < 8; ++e) o.u[e] = T[pc * 8 + e][t];
    *(int4*)&tdst[(size_t)t * R + r0 + pc * 8] = o.v;
  }
}

// ---------------- k_scoreA (grid NB*16, 1024 thr = 16 waves): 64 p-rows x 256 q.
// Wave = 16-row strip (s=wv>>2) x 64-q quarter (h=wv&3). dbuf staging.
__global__ __launch_bounds__(1024) void k_scoreA(
    const unsigned short* __restrict__ Pw, const unsigned short* __restrict__ Qb,
    const unsigned short* __restrict__ QbT,
    const float* __restrict__ sp, const float* __restrict__ sq,
    const int* __restrict__ pmask, const int* __restrict__ qmask,
    const float* __restrict__ bias,
    __half* __restrict__ S16, float* __restrict__ CM, float* __restrict__ CL,
    unsigned short* __restrict__ P2Q, float* __restrict__ out1) {
  int bid = blockIdx.x;
  int b = bid >> 4;
  int tile = bid & 15;
  int p0 = tile * 64;
  int t = threadIdx.x, lane = t & 63, wv = t >> 6;   // 16 waves
  int s = wv >> 2, h = wv & 3;                        // strip 0..3 (16 rows), quarter 0..3 (64 q)
  __shared__ __align__(16) unsigned short As[2][64][40];
  __shared__ __align__(16) unsigned short Bs[2][256][40];
  __shared__ __align__(16) unsigned short Pl[64][264];   // fp16 S staging, then bf16 P
  __shared__ float redM[4][256], redL[4][256];
  __shared__ float rowM[64][4], rowL[64][4];

  // staging (per 32-wide K slice): Bs 256x32 (one int4/thread), As 64x32 (t<256)
  int rb = t >> 2, cb = (t & 3) * 8;

  // ---- phase 1: score GEMM (64 x 256, K = 256), dbuf
  f32x4 acc[4] = {};
  int4 rbv, rav;
  rbv = *(const int4*)&Qb[((size_t)b * QLEN + rb) * DIM + cb];
  if (t < 256) rav = *(const int4*)&Pw[((size_t)b * PLEN + p0 + rb) * DIM + cb];
  *(int4*)&Bs[0][rb][cb] = rbv;
  if (t < 256) *(int4*)&As[0][rb][cb] = rav;
  __syncthreads();
  int cur = 0;
  for (int ki = 0; ki < 8; ++ki) {
    if (ki < 7) {
      int kt = (ki + 1) * 32;
      rbv = *(const int4*)&Qb[((size_t)b * QLEN + rb) * DIM + kt + cb];
      if (t < 256) rav = *(const int4*)&Pw[((size_t)b * PLEN + p0 + rb) * DIM + kt + cb];
    }
    short8 af = *(const short8*)&As[cur][s * 16 + (lane & 15)][(lane >> 4) * 8];
    for (int j = 0; j < 4; ++j) {
      short8 bf = *(const short8*)&Bs[cur][h * 64 + j * 16 + (lane & 15)][(lane >> 4) * 8];
      acc[j] = __builtin_amdgcn_mfma_f32_16x16x32_bf16(af, bf, acc[j], 0, 0, 0);
    }
    if (ki < 7) {
      int nxt = cur ^ 1;
      *(int4*)&Bs[nxt][rb][cb] = rbv;
      if (t < 256) *(int4*)&As[nxt][rb][cb] = rav;
      cur = nxt;
    }
    __syncthreads();
  }

  // ---- phase 2: bias + mask epilogue; stage fp16 S tile in Pl
  float b0 = bias[0];
  int prow[4]; float spv[4]; int pmv[4];
  for (int r = 0; r < 4; ++r) {
    prow[r] = p0 + s * 16 + (lane >> 4) * 4 + r;
    spv[r] = sp[b * PLEN + prow[r]] + b0;
    pmv[r] = pmask[b * PLEN + prow[r]];
  }
  float sqv[4]; int qmv[4];
  for (int j = 0; j < 4; ++j) {
    int q = h * 64 + j * 16 + (lane & 15);
    sqv[j] = sq[b * QLEN + q];
    qmv[j] = qmask[b * QLEN + q];
  }
  for (int j = 0; j < 4; ++j) {
    int q = h * 64 + j * 16 + (lane & 15);
    for (int r = 0; r < 4; ++r) {
      float v = acc[j][r] + spv[r] + sqv[j];
      if (pmv[r] | qmv[j]) v = MASKV;
      acc[j][r] = v;
      int rl = s * 16 + (lane >> 4) * 4 + r;
      Pl[rl][q] = __half_as_ushort(__float2half(v));
    }
  }

  // ---- phase 3a: column partials (per strip) + row partials (per quarter)
  for (int j = 0; j < 4; ++j) {
    float m = fmaxf(fmaxf(acc[j][0], acc[j][1]), fmaxf(acc[j][2], acc[j][3]));
    m = fmaxf(m, __shfl_xor(m, 16, 64));
    m = fmaxf(m, __shfl_xor(m, 32, 64));
    float e = 0.f;
    for (int r = 0; r < 4; ++r) e += __expf(acc[j][r] - m);
    e += __shfl_xor(e, 16, 64);
    e += __shfl_xor(e, 32, 64);
    if ((lane >> 4) == 0) {
      redM[s][h * 64 + j * 16 + (lane & 15)] = m;
      redL[s][h * 64 + j * 16 + (lane & 15)] = e;
    }
  }
  for (int r = 0; r < 4; ++r) {
    int rl = s * 16 + (lane >> 4) * 4 + r;
    float m = acc[0][r];
    for (int j = 1; j < 4; ++j) m = fmaxf(m, acc[j][r]);
    for (int msk = 1; msk <= 8; msk <<= 1) m = fmaxf(m, __shfl_xor(m, msk, 64));
    float l = 0.f;
    for (int j = 0; j < 4; ++j) l += __expf(acc[j][r] - m);
    for (int msk = 1; msk <= 8; msk <<= 1) l += __shfl_xor(l, msk, 64);
    if ((lane & 15) == 0) { rowM[rl][h] = m; rowL[rl][h] = l; }
  }
  __syncthreads();

  // ---- S16 copy-out (coalesced from Pl)
  for (int k = 0; k < 2; ++k) {
    int idx = t + k * 1024;
    int row = idx >> 5, c8 = idx & 31;
    *(int4*)&S16[((size_t)b * PLEN + p0 + row) * QLEN + c8 * 8] = *(const int4*)&Pl[row][c8 * 8];
  }

  // ---- phase 3b: CM/CL store (combine 4 strips)
  if (t < 256) {
    int q = t;
    float M = fmaxf(fmaxf(redM[0][q], redM[1][q]), fmaxf(redM[2][q], redM[3][q]));
    float L = redL[0][q] * __expf(redM[0][q] - M) + redL[1][q] * __expf(redM[1][q] - M)
            + redL[2][q] * __expf(redM[2][q] - M) + redL[3][q] * __expf(redM[3][q] - M);
    size_t o = ((size_t)b * 16 + tile) * QLEN + q;
    CM[o] = M; CL[o] = L;
  }
  __syncthreads();   // S16 copy done before Pl overwrite

  // ---- phase 4: exact row softmax (combine 4 quarters) -> Pl (bf16)
  for (int r = 0; r < 4; ++r) {
    int rl = s * 16 + (lane >> 4) * 4 + r;
    float m0 = rowM[rl][0], m1 = rowM[rl][1], m2 = rowM[rl][2], m3 = rowM[rl][3];
    float m = fmaxf(fmaxf(m0, m1), fmaxf(m2, m3));
    float l = rowL[rl][0] * __expf(m0 - m) + rowL[rl][1] * __expf(m1 - m)
            + rowL[rl][2] * __expf(m2 - m) + rowL[rl][3] * __expf(m3 - m);
    float inv = 1.0f / l;
    for (int j = 0; j < 4; ++j) {
      float e = (pmv[r] | qmv[j]) ? 0.0f : __expf(acc[j][r] - m) * inv;
      Pl[rl][h * 64 + j * 16 + (lane & 15)] = f2bf(e);
    }
  }
  __syncthreads();

  // ---- P2Q global store (coalesced from Pl)
  for (int k = 0; k < 2; ++k) {
    int idx = t + k * 1024;
    int row = idx >> 5, c8 = idx & 31;
    *(int4*)&P2Q[((size_t)b * PLEN + p0 + row) * QLEN + c8 * 8] = *(const int4*)&Pl[row][c8 * 8];
  }

  // ---- phase 5: out1 = P @ QbT^T (K = 256), dbuf over QbT
  f32x4 acc2[4] = {};
  rbv = *(const int4*)&QbT[((size_t)b * DIM + rb) * QLEN + cb];
  *(int4*)&Bs[0][rb][cb] = rbv;
  __syncthreads();
  cur = 0;
  for (int ki = 0; ki < 8; ++ki) {
    if (ki < 7) {
      int kt = (ki + 1) * 32;
      rbv = *(const int4*)&QbT[((size_t)b * DIM + rb) * QLEN + kt + cb];
    }
    short8 af = *(const short8*)&Pl[s * 16 + (lane & 15)][ki * 32 + (lane >> 4) * 8];
    for (int j = 0; j < 4; ++j) {
      short8 bf = *(const short8*)&Bs[cur][h * 64 + j * 16 + (lane & 15)][(lane >> 4) * 8];
      acc2[j] = __builtin_amdgcn_mfma_f32_16x16x32_bf16(af, bf, acc2[j], 0, 0, 0);
    }
    if (ki < 7) {
      int nxt = cur ^ 1;
      *(int4*)&Bs[nxt][rb][cb] = rbv;
      cur = nxt;
    }
    __syncthreads();
  }
  for (int j = 0; j < 4; ++j) {
    int d = h * 64 + j * 16 + (lane & 15);
    for (int r = 0; r < 4; ++r)
      out1[((size_t)b * PLEN + prow[r]) * DIM + d] = acc2[j][r];
  }
}

// ---------------- k_colfinish: W2t[b,q,p] = bf16(exp(S16 - M_q)/L_q); 64q x 64p per block
__global__ __launch_bounds__(256) void k_colfinish(
    const __half* __restrict__ S16,
    const float* __restrict__ CM, const float* __restrict__ CL,
    unsigned short* __restrict__ W2t) {
  int bid = blockIdx.x;
  int b = bid >> 6, qt = (bid >> 4) & 3, pg = bid & 15;
  int q0 = qt * 64, p0 = pg * 64;
  int t = threadIdx.x;
  __shared__ float Mq[64], iLq[64];
  if (t < 64) {
    int q = q0 + t;
    float M = CM[((size_t)b * 16) * QLEN + q];
    for (int tm = 1; tm < 16; ++tm)
      M = fmaxf(M, CM[((size_t)b * 16 + tm) * QLEN + q]);
    float L = 0.f;
    for (int tm = 0; tm < 16; ++tm) {
      size_t o = ((size_t)b * 16 + tm) * QLEN + q;
      L += CL[o] * __expf(CM[o] - M);
    }
    Mq[t] = M; iLq[t] = 1.0f / L;
  }
  __shared__ __align__(16) __half T[64][80];
  for (int k = 0; k < 2; ++k) {
    int idx = t + k * 256;
    int rr = idx >> 3, i4 = idx & 7;
    *(int4*)&T[rr][i4 * 8] =
        *(const int4*)&S16[((size_t)b * PLEN + p0 + rr) * QLEN + q0 + i4 * 8];
  }
  __syncthreads();
  int qq = t >> 2, k4 = t & 3;
  float M = Mq[qq], iL = iLq[qq];
  union { unsigned short u[16]; int4 v[2]; } o;
  for (int e = 0; e < 16; ++e) {
    int pp = k4 * 16 + e;
    float sv = __half2float(T[pp][qq]);
    o.u[e] = f2bf(__expf(sv - M) * iL);
  }
  unsigned short* dst = W2t + ((size_t)b * QLEN + q0 + qq) * PLEN + p0 + k4 * 16;
  *(int4*)dst = o.v[0];
  *(int4*)(dst + 8) = o.v[1];
}

// ---------------- k_gemm_qatt (512 thr, 8 waves): QATTt[b,d,q] = PbT @ W2t^T (K=PLEN), dbuf
__global__ __launch_bounds__(512) void k_gemm_qatt(
    const unsigned short* __restrict__ PbT, const unsigned short* __restrict__ W2t,
    unsigned short* __restrict__ QATTt) {
  int bid = blockIdx.x;
  int b = bid >> 4;
  int tm = (bid >> 2) & 3;
  int tn = bid & 3;
  const unsigned short* A  = PbT + ((size_t)b * DIM + tm * 64) * PLEN;
  const unsigned short* Bm = W2t + ((size_t)b * QLEN + tn * 64) * PLEN;
  __shared__ __align__(16) unsigned short As[2][64][72];
  __shared__ __align__(16) unsigned short Bs[2][64][72];
  int t = threadIdx.x, lane = t & 63, wid = t >> 6;
  int wm = wid >> 2, wn = wid & 3;       // wave = 32 d x 16 q
  f32x4 acc[2] = {};
  int r = t >> 3, g = (t & 7) * 8;       // 64 x 64 per slice, 1 int4 each for A and B
  int4 rav, rbv;
  rav = *(const int4*)&A[(size_t)r * PLEN + g];
  rbv = *(const int4*)&Bm[(size_t)r * PLEN + g];
  *(int4*)&As[0][r][g] = rav;
  *(int4*)&Bs[0][r][g] = rbv;
  __syncthreads();
  int cur = 0;
  for (int ki = 0; ki < 16; ++ki) {
    if (ki < 15) {
      int kt = (ki + 1) * 64;
      rav = *(const int4*)&A[(size_t)r * PLEN + kt + g];
      rbv = *(const int4*)&Bm[(size_t)r * PLEN + kt + g];
    }
    for (int kk = 0; kk < 64; kk += 32) {
      short8 bf = *(const short8*)&Bs[cur][wn * 16 + (lane & 15)][kk + (lane >> 4) * 8];
      for (int i = 0; i < 2; ++i) {
        short8 af = *(const short8*)&As[cur][wm * 32 + i * 16 + (lane & 15)][kk + (lane >> 4) * 8];
        acc[i] = __builtin_amdgcn_mfma_f32_16x16x32_bf16(af, bf, acc[i], 0, 0, 0);
      }
    }
    if (ki < 15) {
      int nxt = cur ^ 1;
      *(int4*)&As[nxt][r][g] = rav;
      *(int4*)&Bs[nxt][r][g] = rbv;
      cur = nxt;
    }
    __syncthreads();
  }
  int d0 = tm * 64 + wm * 32, q0 = tn * 64 + wn * 16;
  for (int i = 0; i < 2; ++i)
    for (int rr = 0; rr < 4; ++rr) {
      int d = d0 + i * 16 + (lane >> 4) * 4 + rr;
      int q = q0 + (lane & 15);
      QATTt[((size_t)b * DIM + d) * QLEN + q] = f2bf(acc[i][rr]);
    }
}

// ---------------- k_gemm_final2 (512 thr, 8 waves): out2 = P2Q @ QATTt^T; 128p x 128d, dbuf
__global__ __launch_bounds__(512) void k_gemm_final2(
    const unsigned short* __restrict__ P2Q, const unsigned short* __restrict__ QATTt,
    float* __restrict__ out2) {
  int bid = blockIdx.x;
  int b = bid >> 4;
  int tm = (bid >> 1) & 7;
  int tn = bid & 1;
  const unsigned short* A  = P2Q + ((size_t)b * PLEN + tm * 128) * QLEN;
  const unsigned short* B2 = QATTt + ((size_t)b * DIM + tn * 128) * QLEN;
  __shared__ __align__(16) unsigned short As[2][128][40];
  __shared__ __align__(16) unsigned short Bc[2][128][40];
  int t = threadIdx.x, lane = t & 63, wid = t >> 6;
  int wm = wid >> 2, wn = wid & 3;       // wave = 64 p x 32 d
  f32x4 acc[4][2] = {};
  int r = t >> 2, c = (t & 3) * 8;       // 128 x 32 per slice, 1 int4 each for A and B
  int4 rav, rbv;
  rav = *(const int4*)&A[(size_t)r * QLEN + c];
  rbv = *(const int4*)&B2[(size_t)r * QLEN + c];
  *(int4*)&As[0][r][c] = rav;
  *(int4*)&Bc[0][r][c] = rbv;
  __syncthreads();
  int cur = 0;
  for (int ki = 0; ki < 8; ++ki) {
    if (ki < 7) {
      int kt = (ki + 1) * 32;
      rav = *(const int4*)&A[(size_t)r * QLEN + kt + c];
      rbv = *(const int4*)&B2[(size_t)r * QLEN + kt + c];
    }
    short8 af[4], bc[2];
    for (int i = 0; i < 4; ++i)
      af[i] = *(const short8*)&As[cur][wm * 64 + i * 16 + (lane & 15)][(lane >> 4) * 8];
    for (int j = 0; j < 2; ++j)
      bc[j] = *(const short8*)&Bc[cur][wn * 32 + j * 16 + (lane & 15)][(lane >> 4) * 8];
    for (int i = 0; i < 4; ++i)
      for (int j = 0; j < 2; ++j)
        acc[i][j] = __builtin_amdgcn_mfma_f32_16x16x32_bf16(af[i], bc[j], acc[i][j], 0, 0, 0);
    if (ki < 7) {
      int nxt = cur ^ 1;
      *(int4*)&As[nxt][r][c] = rav;
      *(int4*)&Bc[nxt][r][c] = rbv;
      cur = nxt;
    }
    __syncthreads();
  }
  int p0 = tm * 128 + wm * 64, d0 = tn * 128 + wn * 32;
  for (int i = 0; i < 4; ++i)
    for (int rr = 0; rr < 4; ++rr) {
      int p = p0 + i * 16 + (lane >> 4) * 4 + rr;
      size_t rowo = ((size_t)b * PLEN + p) * DIM;
      for (int j = 0; j < 2; ++j) {
        int d = d0 + j * 16 + (lane & 15);
        out2[rowo + d] = acc[i][j][rr];
      }
    }
}

extern "C" void kernel_launch(void* const* d_in, const int* in_sizes, int n_in,
                              void* d_out, int out_size, void* d_ws, size_t ws_size,
                              hipStream_t stream) {
  const float* passage  = (const float*)d_in[0];
  const float* question = (const float*)d_in[1];
  const int*   pmask    = (const int*)d_in[2];
  const int*   qmask    = (const int*)d_in[3];
  const float* W        = (const float*)d_in[4];
  const float* bias     = (const float*)d_in[5];
  float* out = (float*)d_out;

  const size_t NS = (size_t)NB * PLEN * QLEN;    // 4,194,304
  const size_t NQ = (size_t)NB * QLEN * DIM;     // 1,048,576
  char* w = (char*)d_ws;
  __half* S16 = (__half*)w;                  w += NS * 2;
  unsigned short* Pw   = (unsigned short*)w; w += NS * 2;
  unsigned short* Qb   = (unsigned short*)w; w += NQ * 2;
  unsigned short* PbT  = (unsigned short*)w; w += NS * 2;
  unsigned short* QbT  = (unsigned short*)w; w += NQ * 2;
  unsigned short* P2Q  = (unsigned short*)w; w += NS * 2;
  unsigned short* W2t  = (unsigned short*)w; w += NS * 2;
  unsigned short* QATTt = (unsigned short*)w; w += NQ * 2;
  float* CM = (float*)w;                     w += (size_t)NB * 16 * QLEN * 4;
  float* CL = (float*)w;                     w += (size_t)NB * 16 * QLEN * 4;
  float* sp = (float*)w;                     w += (size_t)NB * PLEN * 4;
  float* sq = (float*)w;

  float* out1 = out;
  float* out2 = out + (size_t)NB * PLEN * DIM;

  k_prep2<<<dim3(NB * 16 + NB * 4), dim3(256), 0, stream>>>(
      passage, question, W, Pw, Qb, PbT, QbT, sp, sq);
  k_scoreA<<<dim3(NB * 16), dim3(1024), 0, stream>>>(
      Pw, Qb, QbT, sp, sq, pmask, qmask, bias, S16, CM, CL, P2Q, out1);
  k_colfinish<<<dim3(NB * 64), dim3(256), 0, stream>>>(
      S16, CM, CL, W2t);
  k_gemm_qatt<<<dim3(NB * 16), dim3(512), 0, stream>>>(
      PbT, W2t, QATTt);
  k_gemm_final2<<<dim3(NB * 16), dim3(512), 0, stream>>>(
      P2Q, QATTt, out2);
}

// Round 10
// 79.018 us; speedup vs baseline: 1.1771x; 1.0038x over previous
//
#include <hip/hip_runtime.h>
#include <hip/hip_fp16.h>
#include <math.h>

#define NB 16
#define PLEN 1024
#define QLEN 256
#define DIM 256
#define MASKV -10000000.0f

typedef __attribute__((ext_vector_type(8))) short short8;
typedef __attribute__((ext_vector_type(4))) float f32x4;

union u4x16 { unsigned short u[4]; int2 v; };
union u8x16 { unsigned short u[8]; int4 v; };

__device__ inline unsigned short f2bf(float x) {
  unsigned int u = __float_as_uint(x);
  u += 0x7FFF + ((u >> 16) & 1);          // round-to-nearest-even
  return (unsigned short)(u >> 16);
}

// ---------------- k_prep2: one pass over passage/question fp32.
__global__ __launch_bounds__(256) void k_prep2(
    const float* __restrict__ passage, const float* __restrict__ question,
    const float* __restrict__ W,
    unsigned short* __restrict__ Pw, unsigned short* __restrict__ Qb,
    unsigned short* __restrict__ PbT, unsigned short* __restrict__ QbT,
    float* __restrict__ sp, float* __restrict__ sq) {
  int bid = blockIdx.x;
  int t = threadIdx.x;
  __shared__ unsigned short T[64][268];
  int isP = bid < NB * 16;
  int b, r0, R;
  const float* src; unsigned short* cast_out; unsigned short* tdst; float* dots;
  const float* wd; const float* wm;
  if (isP) {
    b = bid >> 4; r0 = (bid & 15) * 64; R = PLEN;
    src = passage + ((size_t)b * PLEN + r0) * DIM;
    cast_out = Pw + ((size_t)b * PLEN + r0) * DIM;
    tdst = PbT + (size_t)b * DIM * PLEN;
    dots = sp + b * PLEN + r0;
    wd = W; wm = W + 2 * DIM;
  } else {
    int bq = bid - NB * 16;
    b = bq >> 2; r0 = (bq & 3) * 64; R = QLEN;
    src = question + ((size_t)b * QLEN + r0) * DIM;
    cast_out = Qb + ((size_t)b * QLEN + r0) * DIM;
    tdst = QbT + (size_t)b * DIM * QLEN;
    dots = sq + b * QLEN + r0;
    wd = W + DIM; wm = nullptr;
  }
  int row = t >> 2, c0 = (t & 3) * 64;
  float s = 0.f;
  for (int i = 0; i < 16; ++i) {
    int d = c0 + i * 4;
    float4 x = *(const float4*)&src[(size_t)row * DIM + d];
    s += x.x * wd[d] + x.y * wd[d + 1] + x.z * wd[d + 2] + x.w * wd[d + 3];
    u4x16 tv;
    tv.u[0] = f2bf(x.x); tv.u[1] = f2bf(x.y); tv.u[2] = f2bf(x.z); tv.u[3] = f2bf(x.w);
    *(int2*)&T[row][d] = tv.v;
    u4x16 ov;
    if (isP) {
      ov.u[0] = f2bf(x.x * wm[d]);     ov.u[1] = f2bf(x.y * wm[d + 1]);
      ov.u[2] = f2bf(x.z * wm[d + 2]); ov.u[3] = f2bf(x.w * wm[d + 3]);
    } else ov = tv;
    *(int2*)&cast_out[(size_t)row * DIM + d] = ov.v;
  }
  s += __shfl_xor(s, 1, 64);
  s += __shfl_xor(s, 2, 64);
  if ((t & 3) == 0) dots[row] = s;
  __syncthreads();
  for (int pc = 0; pc < 8; ++pc) {
    u8x16 o;
    for (int e = 0; e < 8; ++e) o.u[e] = T[pc * 8 + e][t];
    *(int4*)&tdst[(size_t)t * R + r0 + pc * 8] = o.v;
  }
}

// ---------------- k_scoreA (grid NB*16, 1024 thr = 16 waves): 64 p-rows x 256 q.
// score GEMM + mask + S16 + col partials + exact row softmax -> P2Q.  (out1 moved to final2)
__global__ __launch_bounds__(1024) void k_scoreA(
    const unsigned short* __restrict__ Pw, const unsigned short* __restrict__ Qb,
    const float* __restrict__ sp, const float* __restrict__ sq,
    const int* __restrict__ pmask, const int* __restrict__ qmask,
    const float* __restrict__ bias,
    __half* __restrict__ S16, float* __restrict__ CM, float* __restrict__ CL,
    unsigned short* __restrict__ P2Q) {
  int bid = blockIdx.x;
  int b = bid >> 4;
  int tile = bid & 15;
  int p0 = tile * 64;
  int t = threadIdx.x, lane = t & 63, wv = t >> 6;   // 16 waves
  int s = wv >> 2, h = wv & 3;                        // strip 0..3 (16 rows), quarter 0..3 (64 q)
  __shared__ __align__(16) unsigned short As[2][64][40];
  __shared__ __align__(16) unsigned short Bs[2][256][40];
  __shared__ __align__(16) unsigned short Pl[64][264];   // fp16 S staging, then bf16 P
  __shared__ float redM[4][256], redL[4][256];
  __shared__ float rowM[64][4], rowL[64][4];

  int rb = t >> 2, cb = (t & 3) * 8;

  // ---- phase 1: score GEMM (64 x 256, K = 256), dbuf
  f32x4 acc[4] = {};
  int4 rbv, rav;
  rbv = *(const int4*)&Qb[((size_t)b * QLEN + rb) * DIM + cb];
  if (t < 256) rav = *(const int4*)&Pw[((size_t)b * PLEN + p0 + rb) * DIM + cb];
  *(int4*)&Bs[0][rb][cb] = rbv;
  if (t < 256) *(int4*)&As[0][rb][cb] = rav;
  __syncthreads();
  int cur = 0;
  for (int ki = 0; ki < 8; ++ki) {
    if (ki < 7) {
      int kt = (ki + 1) * 32;
      rbv = *(const int4*)&Qb[((size_t)b * QLEN + rb) * DIM + kt + cb];
      if (t < 256) rav = *(const int4*)&Pw[((size_t)b * PLEN + p0 + rb) * DIM + kt + cb];
    }
    short8 af = *(const short8*)&As[cur][s * 16 + (lane & 15)][(lane >> 4) * 8];
    for (int j = 0; j < 4; ++j) {
      short8 bf = *(const short8*)&Bs[cur][h * 64 + j * 16 + (lane & 15)][(lane >> 4) * 8];
      acc[j] = __builtin_amdgcn_mfma_f32_16x16x32_bf16(af, bf, acc[j], 0, 0, 0);
    }
    if (ki < 7) {
      int nxt = cur ^ 1;
      *(int4*)&Bs[nxt][rb][cb] = rbv;
      if (t < 256) *(int4*)&As[nxt][rb][cb] = rav;
      cur = nxt;
    }
    __syncthreads();
  }

  // ---- phase 2: bias + mask epilogue; stage fp16 S tile in Pl
  float b0 = bias[0];
  int prow[4]; float spv[4]; int pmv[4];
  for (int r = 0; r < 4; ++r) {
    prow[r] = p0 + s * 16 + (lane >> 4) * 4 + r;
    spv[r] = sp[b * PLEN + prow[r]] + b0;
    pmv[r] = pmask[b * PLEN + prow[r]];
  }
  float sqv[4]; int qmv[4];
  for (int j = 0; j < 4; ++j) {
    int q = h * 64 + j * 16 + (lane & 15);
    sqv[j] = sq[b * QLEN + q];
    qmv[j] = qmask[b * QLEN + q];
  }
  for (int j = 0; j < 4; ++j) {
    int q = h * 64 + j * 16 + (lane & 15);
    for (int r = 0; r < 4; ++r) {
      float v = acc[j][r] + spv[r] + sqv[j];
      if (pmv[r] | qmv[j]) v = MASKV;
      acc[j][r] = v;
      int rl = s * 16 + (lane >> 4) * 4 + r;
      Pl[rl][q] = __half_as_ushort(__float2half(v));
    }
  }

  // ---- phase 3a: column partials (per strip) + row partials (per quarter)
  for (int j = 0; j < 4; ++j) {
    float m = fmaxf(fmaxf(acc[j][0], acc[j][1]), fmaxf(acc[j][2], acc[j][3]));
    m = fmaxf(m, __shfl_xor(m, 16, 64));
    m = fmaxf(m, __shfl_xor(m, 32, 64));
    float e = 0.f;
    for (int r = 0; r < 4; ++r) e += __expf(acc[j][r] - m);
    e += __shfl_xor(e, 16, 64);
    e += __shfl_xor(e, 32, 64);
    if ((lane >> 4) == 0) {
      redM[s][h * 64 + j * 16 + (lane & 15)] = m;
      redL[s][h * 64 + j * 16 + (lane & 15)] = e;
    }
  }
  for (int r = 0; r < 4; ++r) {
    int rl = s * 16 + (lane >> 4) * 4 + r;
    float m = acc[0][r];
    for (int j = 1; j < 4; ++j) m = fmaxf(m, acc[j][r]);
    for (int msk = 1; msk <= 8; msk <<= 1) m = fmaxf(m, __shfl_xor(m, msk, 64));
    float l = 0.f;
    for (int j = 0; j < 4; ++j) l += __expf(acc[j][r] - m);
    for (int msk = 1; msk <= 8; msk <<= 1) l += __shfl_xor(l, msk, 64);
    if ((lane & 15) == 0) { rowM[rl][h] = m; rowL[rl][h] = l; }
  }
  __syncthreads();

  // ---- S16 copy-out (coalesced from Pl)
  for (int k = 0; k < 2; ++k) {
    int idx = t + k * 1024;
    int row = idx >> 5, c8 = idx & 31;
    *(int4*)&S16[((size_t)b * PLEN + p0 + row) * QLEN + c8 * 8] = *(const int4*)&Pl[row][c8 * 8];
  }

  // ---- phase 3b: CM/CL store (combine 4 strips)
  if (t < 256) {
    int q = t;
    float M = fmaxf(fmaxf(redM[0][q], redM[1][q]), fmaxf(redM[2][q], redM[3][q]));
    float L = redL[0][q] * __expf(redM[0][q] - M) + redL[1][q] * __expf(redM[1][q] - M)
            + redL[2][q] * __expf(redM[2][q] - M) + redL[3][q] * __expf(redM[3][q] - M);
    size_t o = ((size_t)b * 16 + tile) * QLEN + q;
    CM[o] = M; CL[o] = L;
  }
  __syncthreads();   // S16 copy done before Pl overwrite

  // ---- phase 4: exact row softmax (combine 4 quarters) -> Pl (bf16)
  for (int r = 0; r < 4; ++r) {
    int rl = s * 16 + (lane >> 4) * 4 + r;
    float m0 = rowM[rl][0], m1 = rowM[rl][1], m2 = rowM[rl][2], m3 = rowM[rl][3];
    float m = fmaxf(fmaxf(m0, m1), fmaxf(m2, m3));
    float l = rowL[rl][0] * __expf(m0 - m) + rowL[rl][1] * __expf(m1 - m)
            + rowL[rl][2] * __expf(m2 - m) + rowL[rl][3] * __expf(m3 - m);
    float inv = 1.0f / l;
    for (int j = 0; j < 4; ++j) {
      float e = (pmv[r] | qmv[j]) ? 0.0f : __expf(acc[j][r] - m) * inv;
      Pl[rl][h * 64 + j * 16 + (lane & 15)] = f2bf(e);
    }
  }
  __syncthreads();

  // ---- P2Q global store (coalesced from Pl)
  for (int k = 0; k < 2; ++k) {
    int idx = t + k * 1024;
    int row = idx >> 5, c8 = idx & 31;
    *(int4*)&P2Q[((size_t)b * PLEN + p0 + row) * QLEN + c8 * 8] = *(const int4*)&Pl[row][c8 * 8];
  }
}

// ---------------- k_colfinish: W2t[b,q,p] = bf16(exp(S16 - M_q)/L_q); 64q x 64p per block
__global__ __launch_bounds__(256) void k_colfinish(
    const __half* __restrict__ S16,
    const float* __restrict__ CM, const float* __restrict__ CL,
    unsigned short* __restrict__ W2t) {
  int bid = blockIdx.x;
  int b = bid >> 6, qt = (bid >> 4) & 3, pg = bid & 15;
  int q0 = qt * 64, p0 = pg * 64;
  int t = threadIdx.x;
  __shared__ float Mq[64], iLq[64];
  if (t < 64) {
    int q = q0 + t;
    float M = CM[((size_t)b * 16) * QLEN + q];
    for (int tm = 1; tm < 16; ++tm)
      M = fmaxf(M, CM[((size_t)b * 16 + tm) * QLEN + q]);
    float L = 0.f;
    for (int tm = 0; tm < 16; ++tm) {
      size_t o = ((size_t)b * 16 + tm) * QLEN + q;
      L += CL[o] * __expf(CM[o] - M);
    }
    Mq[t] = M; iLq[t] = 1.0f / L;
  }
  __shared__ __align__(16) __half T[64][80];
  for (int k = 0; k < 2; ++k) {
    int idx = t + k * 256;
    int rr = idx >> 3, i4 = idx & 7;
    *(int4*)&T[rr][i4 * 8] =
        *(const int4*)&S16[((size_t)b * PLEN + p0 + rr) * QLEN + q0 + i4 * 8];
  }
  __syncthreads();
  int qq = t >> 2, k4 = t & 3;
  float M = Mq[qq], iL = iLq[qq];
  union { unsigned short u[16]; int4 v[2]; } o;
  for (int e = 0; e < 16; ++e) {
    int pp = k4 * 16 + e;
    float sv = __half2float(T[pp][qq]);
    o.u[e] = f2bf(__expf(sv - M) * iL);
  }
  unsigned short* dst = W2t + ((size_t)b * QLEN + q0 + qq) * PLEN + p0 + k4 * 16;
  *(int4*)dst = o.v[0];
  *(int4*)(dst + 8) = o.v[1];
}

// ---------------- k_gemm_qatt (512 thr, 8 waves): QATTt[b,d,q] = PbT @ W2t^T (K=PLEN), dbuf
__global__ __launch_bounds__(512) void k_gemm_qatt(
    const unsigned short* __restrict__ PbT, const unsigned short* __restrict__ W2t,
    unsigned short* __restrict__ QATTt) {
  int bid = blockIdx.x;
  int b = bid >> 4;
  int tm = (bid >> 2) & 3;
  int tn = bid & 3;
  const unsigned short* A  = PbT + ((size_t)b * DIM + tm * 64) * PLEN;
  const unsigned short* Bm = W2t + ((size_t)b * QLEN + tn * 64) * PLEN;
  __shared__ __align__(16) unsigned short As[2][64][72];
  __shared__ __align__(16) unsigned short Bs[2][64][72];
  int t = threadIdx.x, lane = t & 63, wid = t >> 6;
  int wm = wid >> 2, wn = wid & 3;       // wave = 32 d x 16 q
  f32x4 acc[2] = {};
  int r = t >> 3, g = (t & 7) * 8;
  int4 rav, rbv;
  rav = *(const int4*)&A[(size_t)r * PLEN + g];
  rbv = *(const int4*)&Bm[(size_t)r * PLEN + g];
  *(int4*)&As[0][r][g] = rav;
  *(int4*)&Bs[0][r][g] = rbv;
  __syncthreads();
  int cur = 0;
  for (int ki = 0; ki < 16; ++ki) {
    if (ki < 15) {
      int kt = (ki + 1) * 64;
      rav = *(const int4*)&A[(size_t)r * PLEN + kt + g];
      rbv = *(const int4*)&Bm[(size_t)r * PLEN + kt + g];
    }
    for (int kk = 0; kk < 64; kk += 32) {
      short8 bf = *(const short8*)&Bs[cur][wn * 16 + (lane & 15)][kk + (lane >> 4) * 8];
      for (int i = 0; i < 2; ++i) {
        short8 af = *(const short8*)&As[cur][wm * 32 + i * 16 + (lane & 15)][kk + (lane >> 4) * 8];
        acc[i] = __builtin_amdgcn_mfma_f32_16x16x32_bf16(af, bf, acc[i], 0, 0, 0);
      }
    }
    if (ki < 15) {
      int nxt = cur ^ 1;
      *(int4*)&As[nxt][r][g] = rav;
      *(int4*)&Bs[nxt][r][g] = rbv;
      cur = nxt;
    }
    __syncthreads();
  }
  int d0 = tm * 64 + wm * 32, q0 = tn * 64 + wn * 16;
  for (int i = 0; i < 2; ++i)
    for (int rr = 0; rr < 4; ++rr) {
      int d = d0 + i * 16 + (lane >> 4) * 4 + rr;
      int q = q0 + (lane & 15);
      QATTt[((size_t)b * DIM + d) * QLEN + q] = f2bf(acc[i][rr]);
    }
}

// ---------------- k_gemm_final (512 thr, 8 waves): shared-A dual-B
//   out1 = P2Q @ QbT^T ; out2 = P2Q @ QATTt^T ; 128p x 128d per block, dbuf
__global__ __launch_bounds__(512) void k_gemm_final(
    const unsigned short* __restrict__ P2Q, const unsigned short* __restrict__ QbT,
    const unsigned short* __restrict__ QATTt, float* __restrict__ out) {
  int bid = blockIdx.x;
  int b = bid >> 4;
  int tm = (bid >> 1) & 7;
  int tn = bid & 1;
  const unsigned short* A  = P2Q + ((size_t)b * PLEN + tm * 128) * QLEN;
  const unsigned short* B1 = QbT + ((size_t)b * DIM + tn * 128) * QLEN;
  const unsigned short* B2 = QATTt + ((size_t)b * DIM + tn * 128) * QLEN;
  __shared__ __align__(16) unsigned short As[2][128][40];
  __shared__ __align__(16) unsigned short Bq[2][128][40];
  __shared__ __align__(16) unsigned short Bc[2][128][40];
  int t = threadIdx.x, lane = t & 63, wid = t >> 6;
  int wm = wid >> 2, wn = wid & 3;       // wave = 64 p x 32 d
  f32x4 acc1[4][2] = {}, acc2[4][2] = {};
  int r = t >> 2, c = (t & 3) * 8;       // 128 x 32 per slice, 1 int4 per panel
  int4 rav, rb1, rb2;
  rav = *(const int4*)&A[(size_t)r * QLEN + c];
  rb1 = *(const int4*)&B1[(size_t)r * QLEN + c];
  rb2 = *(const int4*)&B2[(size_t)r * QLEN + c];
  *(int4*)&As[0][r][c] = rav;
  *(int4*)&Bq[0][r][c] = rb1;
  *(int4*)&Bc[0][r][c] = rb2;
  __syncthreads();
  int cur = 0;
  for (int ki = 0; ki < 8; ++ki) {
    if (ki < 7) {
      int kt = (ki + 1) * 32;
      rav = *(const int4*)&A[(size_t)r * QLEN + kt + c];
      rb1 = *(const int4*)&B1[(size_t)r * QLEN + kt + c];
      rb2 = *(const int4*)&B2[(size_t)r * QLEN + kt + c];
    }
    short8 af[4], b1[2], b2[2];
    for (int i = 0; i < 4; ++i)
      af[i] = *(const short8*)&As[cur][wm * 64 + i * 16 + (lane & 15)][(lane >> 4) * 8];
    for (int j = 0; j < 2; ++j) {
      b1[j] = *(const short8*)&Bq[cur][wn * 32 + j * 16 + (lane & 15)][(lane >> 4) * 8];
      b2[j] = *(const short8*)&Bc[cur][wn * 32 + j * 16 + (lane & 15)][(lane >> 4) * 8];
    }
    for (int i = 0; i < 4; ++i)
      for (int j = 0; j < 2; ++j) {
        acc1[i][j] = __builtin_amdgcn_mfma_f32_16x16x32_bf16(af[i], b1[j], acc1[i][j], 0, 0, 0);
        acc2[i][j] = __builtin_amdgcn_mfma_f32_16x16x32_bf16(af[i], b2[j], acc2[i][j], 0, 0, 0);
      }
    if (ki < 7) {
      int nxt = cur ^ 1;
      *(int4*)&As[nxt][r][c] = rav;
      *(int4*)&Bq[nxt][r][c] = rb1;
      *(int4*)&Bc[nxt][r][c] = rb2;
      cur = nxt;
    }
    __syncthreads();
  }
  float* out1 = out;
  float* out2 = out + (size_t)NB * PLEN * DIM;
  int p0 = tm * 128 + wm * 64, d0 = tn * 128 + wn * 32;
  for (int i = 0; i < 4; ++i)
    for (int rr = 0; rr < 4; ++rr) {
      int p = p0 + i * 16 + (lane >> 4) * 4 + rr;
      size_t rowo = ((size_t)b * PLEN + p) * DIM;
      for (int j = 0; j < 2; ++j) {
        int d = d0 + j * 16 + (lane & 15);
        out1[rowo + d] = acc1[i][j][rr];
        out2[rowo + d] = acc2[i][j][rr];
      }
    }
}

extern "C" void kernel_launch(void* const* d_in, const int* in_sizes, int n_in,
                              void* d_out, int out_size, void* d_ws, size_t ws_size,
                              hipStream_t stream) {
  const float* passage  = (const float*)d_in[0];
  const float* question = (const float*)d_in[1];
  const int*   pmask    = (const int*)d_in[2];
  const int*   qmask    = (const int*)d_in[3];
  const float* W        = (const float*)d_in[4];
  const float* bias     = (const float*)d_in[5];
  float* out = (float*)d_out;

  const size_t NS = (size_t)NB * PLEN * QLEN;    // 4,194,304
  const size_t NQ = (size_t)NB * QLEN * DIM;     // 1,048,576
  char* w = (char*)d_ws;
  __half* S16 = (__half*)w;                  w += NS * 2;
  unsigned short* Pw   = (unsigned short*)w; w += NS * 2;
  unsigned short* Qb   = (unsigned short*)w; w += NQ * 2;
  unsigned short* PbT  = (unsigned short*)w; w += NS * 2;
  unsigned short* QbT  = (unsigned short*)w; w += NQ * 2;
  unsigned short* P2Q  = (unsigned short*)w; w += NS * 2;
  unsigned short* W2t  = (unsigned short*)w; w += NS * 2;
  unsigned short* QATTt = (unsigned short*)w; w += NQ * 2;
  float* CM = (float*)w;                     w += (size_t)NB * 16 * QLEN * 4;
  float* CL = (float*)w;                     w += (size_t)NB * 16 * QLEN * 4;
  float* sp = (float*)w;                     w += (size_t)NB * PLEN * 4;
  float* sq = (float*)w;

  k_prep2<<<dim3(NB * 16 + NB * 4), dim3(256), 0, stream>>>(
      passage, question, W, Pw, Qb, PbT, QbT, sp, sq);
  k_scoreA<<<dim3(NB * 16), dim3(1024), 0, stream>>>(
      Pw, Qb, sp, sq, pmask, qmask, bias, S16, CM, CL, P2Q);
  k_colfinish<<<dim3(NB * 64), dim3(256), 0, stream>>>(
      S16, CM, CL, W2t);
  k_gemm_qatt<<<dim3(NB * 16), dim3(512), 0, stream>>>(
      PbT, W2t, QATTt);
  k_gemm_final<<<dim3(NB * 16), dim3(512), 0, stream>>>(
      P2Q, QbT, QATTt, out);
}

// Round 11
// 74.577 us; speedup vs baseline: 1.2472x; 1.0595x over previous
//
#include <hip/hip_runtime.h>
#include <math.h>

#define NB 16
#define PLEN 1024
#define QLEN 256
#define DIM 256
#define MASKV -10000000.0f

typedef __attribute__((ext_vector_type(8))) short short8;
typedef __attribute__((ext_vector_type(4))) float f32x4;

union u4x16 { unsigned short u[4]; int2 v; };
union u8x16 { unsigned short u[8]; int4 v; };

__device__ inline unsigned short f2bf(float x) {
  unsigned int u = __float_as_uint(x);
  u += 0x7FFF + ((u >> 16) & 1);          // round-to-nearest-even
  return (unsigned short)(u >> 16);
}
__device__ inline float bf2f(unsigned short u) {
  return __uint_as_float(((unsigned int)u) << 16);
}

// ---------------- k_prep2: one pass over passage/question fp32.
__global__ __launch_bounds__(256) void k_prep2(
    const float* __restrict__ passage, const float* __restrict__ question,
    const float* __restrict__ W,
    unsigned short* __restrict__ Pw, unsigned short* __restrict__ Qb,
    unsigned short* __restrict__ PbT, unsigned short* __restrict__ QbT,
    float* __restrict__ sp, float* __restrict__ sq) {
  int bid = blockIdx.x;
  int t = threadIdx.x;
  __shared__ unsigned short T[64][268];
  int isP = bid < NB * 16;
  int b, r0, R;
  const float* src; unsigned short* cast_out; unsigned short* tdst; float* dots;
  const float* wd; const float* wm;
  if (isP) {
    b = bid >> 4; r0 = (bid & 15) * 64; R = PLEN;
    src = passage + ((size_t)b * PLEN + r0) * DIM;
    cast_out = Pw + ((size_t)b * PLEN + r0) * DIM;
    tdst = PbT + (size_t)b * DIM * PLEN;
    dots = sp + b * PLEN + r0;
    wd = W; wm = W + 2 * DIM;
  } else {
    int bq = bid - NB * 16;
    b = bq >> 2; r0 = (bq & 3) * 64; R = QLEN;
    src = question + ((size_t)b * QLEN + r0) * DIM;
    cast_out = Qb + ((size_t)b * QLEN + r0) * DIM;
    tdst = QbT + (size_t)b * DIM * QLEN;
    dots = sq + b * QLEN + r0;
    wd = W + DIM; wm = nullptr;
  }
  int row = t >> 2, c0 = (t & 3) * 64;
  float s = 0.f;
  for (int i = 0; i < 16; ++i) {
    int d = c0 + i * 4;
    float4 x = *(const float4*)&src[(size_t)row * DIM + d];
    s += x.x * wd[d] + x.y * wd[d + 1] + x.z * wd[d + 2] + x.w * wd[d + 3];
    u4x16 tv;
    tv.u[0] = f2bf(x.x); tv.u[1] = f2bf(x.y); tv.u[2] = f2bf(x.z); tv.u[3] = f2bf(x.w);
    *(int2*)&T[row][d] = tv.v;
    u4x16 ov;
    if (isP) {
      ov.u[0] = f2bf(x.x * wm[d]);     ov.u[1] = f2bf(x.y * wm[d + 1]);
      ov.u[2] = f2bf(x.z * wm[d + 2]); ov.u[3] = f2bf(x.w * wm[d + 3]);
    } else ov = tv;
    *(int2*)&cast_out[(size_t)row * DIM + d] = ov.v;
  }
  s += __shfl_xor(s, 1, 64);
  s += __shfl_xor(s, 2, 64);
  if ((t & 3) == 0) dots[row] = s;
  __syncthreads();
  // transposed write, coalesced: 8 consecutive threads cover one 128-B d-row segment
  for (int it = 0; it < 8; ++it) {
    int g = t + it * 256;
    int d = g >> 3, ch = g & 7;
    u8x16 o;
    for (int e = 0; e < 8; ++e) o.u[e] = T[ch * 8 + e][d];
    *(int4*)&tdst[(size_t)d * R + r0 + ch * 8] = o.v;
  }
}

// ---------------- k_scoreA (grid NB*16, 1024 thr = 16 waves): 64 p-rows x 256 q.
// score GEMM + mask + col partials CM/CL + exact row softmax
// -> P2Q (row-major bf16), P2Qt (transposed bf16), RM/RL (row stats).  No S16.
__global__ __launch_bounds__(1024) void k_scoreA(
    const unsigned short* __restrict__ Pw, const unsigned short* __restrict__ Qb,
    const float* __restrict__ sp, const float* __restrict__ sq,
    const int* __restrict__ pmask, const int* __restrict__ qmask,
    const float* __restrict__ bias,
    float* __restrict__ CM, float* __restrict__ CL,
    float* __restrict__ RM, float* __restrict__ RL,
    unsigned short* __restrict__ P2Q, unsigned short* __restrict__ P2Qt) {
  int bid = blockIdx.x;
  int b = bid >> 4;
  int tile = bid & 15;
  int p0 = tile * 64;
  int t = threadIdx.x, lane = t & 63, wv = t >> 6;   // 16 waves
  int s = wv >> 2, h = wv & 3;                        // strip 0..3 (16 rows), quarter 0..3 (64 q)
  __shared__ __align__(16) unsigned short As[2][64][40];
  __shared__ __align__(16) unsigned short Bs[2][256][40];
  __shared__ __align__(16) unsigned short Pl[64][264];   // bf16 P
  __shared__ float redM[4][256], redL[4][256];
  __shared__ float rowM[64][4], rowL[64][4];

  int rb = t >> 2, cb = (t & 3) * 8;

  // ---- phase 1: score GEMM (64 x 256, K = 256), dbuf
  f32x4 acc[4] = {};
  int4 rbv, rav;
  rbv = *(const int4*)&Qb[((size_t)b * QLEN + rb) * DIM + cb];
  if (t < 256) rav = *(const int4*)&Pw[((size_t)b * PLEN + p0 + rb) * DIM + cb];
  *(int4*)&Bs[0][rb][cb] = rbv;
  if (t < 256) *(int4*)&As[0][rb][cb] = rav;
  __syncthreads();
  int cur = 0;
  for (int ki = 0; ki < 8; ++ki) {
    if (ki < 7) {
      int kt = (ki + 1) * 32;
      rbv = *(const int4*)&Qb[((size_t)b * QLEN + rb) * DIM + kt + cb];
      if (t < 256) rav = *(const int4*)&Pw[((size_t)b * PLEN + p0 + rb) * DIM + kt + cb];
    }
    short8 af = *(const short8*)&As[cur][s * 16 + (lane & 15)][(lane >> 4) * 8];
    for (int j = 0; j < 4; ++j) {
      short8 bf = *(const short8*)&Bs[cur][h * 64 + j * 16 + (lane & 15)][(lane >> 4) * 8];
      acc[j] = __builtin_amdgcn_mfma_f32_16x16x32_bf16(af, bf, acc[j], 0, 0, 0);
    }
    if (ki < 7) {
      int nxt = cur ^ 1;
      *(int4*)&Bs[nxt][rb][cb] = rbv;
      if (t < 256) *(int4*)&As[nxt][rb][cb] = rav;
      cur = nxt;
    }
    __syncthreads();
  }

  // ---- phase 2: bias + mask epilogue (registers only)
  float b0 = bias[0];
  int prow[4]; float spv[4]; int pmv[4];
  for (int r = 0; r < 4; ++r) {
    prow[r] = p0 + s * 16 + (lane >> 4) * 4 + r;
    spv[r] = sp[b * PLEN + prow[r]] + b0;
    pmv[r] = pmask[b * PLEN + prow[r]];
  }
  float sqv[4]; int qmv[4];
  for (int j = 0; j < 4; ++j) {
    int q = h * 64 + j * 16 + (lane & 15);
    sqv[j] = sq[b * QLEN + q];
    qmv[j] = qmask[b * QLEN + q];
  }
  for (int j = 0; j < 4; ++j)
    for (int r = 0; r < 4; ++r) {
      float v = acc[j][r] + spv[r] + sqv[j];
      if (pmv[r] | qmv[j]) v = MASKV;
      acc[j][r] = v;
    }

  // ---- phase 3a: column partials (per strip) + row partials (per quarter)
  for (int j = 0; j < 4; ++j) {
    float m = fmaxf(fmaxf(acc[j][0], acc[j][1]), fmaxf(acc[j][2], acc[j][3]));
    m = fmaxf(m, __shfl_xor(m, 16, 64));
    m = fmaxf(m, __shfl_xor(m, 32, 64));
    float e = 0.f;
    for (int r = 0; r < 4; ++r) e += __expf(acc[j][r] - m);
    e += __shfl_xor(e, 16, 64);
    e += __shfl_xor(e, 32, 64);
    if ((lane >> 4) == 0) {
      redM[s][h * 64 + j * 16 + (lane & 15)] = m;
      redL[s][h * 64 + j * 16 + (lane & 15)] = e;
    }
  }
  for (int r = 0; r < 4; ++r) {
    int rl = s * 16 + (lane >> 4) * 4 + r;
    float m = acc[0][r];
    for (int j = 1; j < 4; ++j) m = fmaxf(m, acc[j][r]);
    for (int msk = 1; msk <= 8; msk <<= 1) m = fmaxf(m, __shfl_xor(m, msk, 64));
    float l = 0.f;
    for (int j = 0; j < 4; ++j) l += __expf(acc[j][r] - m);
    for (int msk = 1; msk <= 8; msk <<= 1) l += __shfl_xor(l, msk, 64);
    if ((lane & 15) == 0) { rowM[rl][h] = m; rowL[rl][h] = l; }
  }
  __syncthreads();

  // ---- phase 3b: CM/CL store (combine 4 strips)
  if (t < 256) {
    int q = t;
    float M = fmaxf(fmaxf(redM[0][q], redM[1][q]), fmaxf(redM[2][q], redM[3][q]));
    float L = redL[0][q] * __expf(redM[0][q] - M) + redL[1][q] * __expf(redM[1][q] - M)
            + redL[2][q] * __expf(redM[2][q] - M) + redL[3][q] * __expf(redM[3][q] - M);
    size_t o = ((size_t)b * 16 + tile) * QLEN + q;
    CM[o] = M; CL[o] = L;
  }

  // ---- phase 4: exact row softmax (combine 4 quarters) -> Pl (bf16) + RM/RL
  for (int r = 0; r < 4; ++r) {
    int rl = s * 16 + (lane >> 4) * 4 + r;
    float m0 = rowM[rl][0], m1 = rowM[rl][1], m2 = rowM[rl][2], m3 = rowM[rl][3];
    float m = fmaxf(fmaxf(m0, m1), fmaxf(m2, m3));
    float l = rowL[rl][0] * __expf(m0 - m) + rowL[rl][1] * __expf(m1 - m)
            + rowL[rl][2] * __expf(m2 - m) + rowL[rl][3] * __expf(m3 - m);
    if (h == 0 && (lane & 15) == 0) {
      RM[(size_t)b * PLEN + p0 + rl] = m;
      RL[(size_t)b * PLEN + p0 + rl] = l;
    }
    float inv = 1.0f / l;
    for (int j = 0; j < 4; ++j) {
      float e = (pmv[r] | qmv[j]) ? 0.0f : __expf(acc[j][r] - m) * inv;
      Pl[rl][h * 64 + j * 16 + (lane & 15)] = f2bf(e);
    }
  }
  __syncthreads();

  // ---- P2Q row-major store (coalesced from Pl)
  for (int k = 0; k < 2; ++k) {
    int idx = t + k * 1024;
    int row = idx >> 5, c8 = idx & 31;
    *(int4*)&P2Q[((size_t)b * PLEN + p0 + row) * QLEN + c8 * 8] = *(const int4*)&Pl[row][c8 * 8];
  }
  // ---- P2Qt transposed store: thread (q = t>>2, pc = t&3) gathers a 16-p column run
  {
    int q = t >> 2, pc = t & 3;
    union { unsigned short u[16]; int4 v[2]; } o;
    for (int e = 0; e < 16; ++e) o.u[e] = Pl[pc * 16 + e][q];
    unsigned short* dst = P2Qt + ((size_t)b * QLEN + q) * PLEN + p0 + pc * 16;
    *(int4*)dst = o.v[0];
    *(int4*)(dst + 8) = o.v[1];
  }
}

// ---------------- k_qatt2 (512 thr, 8 waves): fused col-softmax + GEMM.
//   W2[p,q] = P2Q[p,q] * RL[p] * exp(RM[p] - Mq) * iLq   (computed on the fly)
//   QATTt[b,d,q] = sum_p PbT[d,p] * W2[p,q]
__global__ __launch_bounds__(512) void k_qatt2(
    const unsigned short* __restrict__ P2Qt, const unsigned short* __restrict__ PbT,
    const float* __restrict__ RM, const float* __restrict__ RL,
    const float* __restrict__ CM, const float* __restrict__ CL,
    unsigned short* __restrict__ QATTt) {
  int bid = blockIdx.x;
  int b = bid >> 4, dt = (bid >> 2) & 3, qt = bid & 3;
  int t = threadIdx.x, lane = t & 63, wid = t >> 6;
  int wm = wid >> 2, wn = wid & 3;                 // wave = 32 d x 16 q
  __shared__ __align__(16) unsigned short Wt[64][72];
  __shared__ __align__(16) unsigned short At[64][72];
  __shared__ float MqS[64], iLqS[64];
  if (t < 64) {
    int q = qt * 64 + t;
    float M = CM[((size_t)b * 16) * QLEN + q];
    for (int tm = 1; tm < 16; ++tm)
      M = fmaxf(M, CM[((size_t)b * 16 + tm) * QLEN + q]);
    float L = 0.f;
    for (int tm = 0; tm < 16; ++tm) {
      size_t o = ((size_t)b * 16 + tm) * QLEN + q;
      L += CL[o] * __expf(CM[o] - M);
    }
    MqS[t] = (M < -1.0e6f) ? 1.0e30f : M;          // masked column -> exp() == 0
    iLqS[t] = 1.0f / L;
  }
  __syncthreads();

  int rrow = t >> 3;            // 0..63: q-row for Wt, d-row for At
  int pch = (t & 7) * 8;        // p-chunk within 64-p slice
  const unsigned short* Wsrc = P2Qt + ((size_t)b * QLEN + qt * 64 + rrow) * PLEN + pch;
  const unsigned short* Asrc = PbT + ((size_t)b * DIM + dt * 64 + rrow) * PLEN + pch;
  const float* rmB = RM + (size_t)b * PLEN + pch;
  const float* rlB = RL + (size_t)b * PLEN + pch;
  float Mq = MqS[rrow], giL = iLqS[rrow];

  f32x4 acc[2] = {};
  int4 wv = *(const int4*)Wsrc;
  int4 av = *(const int4*)Asrc;
  float4 rm0 = *(const float4*)rmB, rm1 = *(const float4*)(rmB + 4);
  float4 rl0 = *(const float4*)rlB, rl1 = *(const float4*)(rlB + 4);

  for (int ps = 0; ps < 16; ++ps) {
    float rmv[8] = {rm0.x, rm0.y, rm0.z, rm0.w, rm1.x, rm1.y, rm1.z, rm1.w};
    float rlv[8] = {rl0.x, rl0.y, rl0.z, rl0.w, rl1.x, rl1.y, rl1.z, rl1.w};
    const unsigned short* wu = (const unsigned short*)&wv;
    u8x16 wo;
#pragma unroll
    for (int e = 0; e < 8; ++e) {
      float w = bf2f(wu[e]) * rlv[e] * __expf(rmv[e] - Mq) * giL;
      wo.u[e] = f2bf(w);
    }
    *(int4*)&Wt[rrow][pch] = wo.v;
    *(int4*)&At[rrow][pch] = av;
    if (ps < 15) {
      int off = (ps + 1) * 64;
      wv = *(const int4*)(Wsrc + off);
      av = *(const int4*)(Asrc + off);
      rm0 = *(const float4*)(rmB + off); rm1 = *(const float4*)(rmB + off + 4);
      rl0 = *(const float4*)(rlB + off); rl1 = *(const float4*)(rlB + off + 4);
    }
    __syncthreads();
    for (int kk = 0; kk < 64; kk += 32) {
      short8 bf = *(const short8*)&Wt[wn * 16 + (lane & 15)][kk + (lane >> 4) * 8];
      for (int i = 0; i < 2; ++i) {
        short8 af = *(const short8*)&At[wm * 32 + i * 16 + (lane & 15)][kk + (lane >> 4) * 8];
        acc[i] = __builtin_amdgcn_mfma_f32_16x16x32_bf16(af, bf, acc[i], 0, 0, 0);
      }
    }
    __syncthreads();
  }
  int d0 = dt * 64 + wm * 32, q0 = qt * 64 + wn * 16;
  for (int i = 0; i < 2; ++i)
    for (int rr = 0; rr < 4; ++rr) {
      int d = d0 + i * 16 + (lane >> 4) * 4 + rr;
      QATTt[((size_t)b * DIM + d) * QLEN + q0 + (lane & 15)] = f2bf(acc[i][rr]);
    }
}

// ---------------- k_gemm_final (512 thr, 8 waves): shared-A dual-B
//   out1 = P2Q @ QbT^T ; out2 = P2Q @ QATTt^T ; 128p x 128d per block, dbuf
__global__ __launch_bounds__(512) void k_gemm_final(
    const unsigned short* __restrict__ P2Q, const unsigned short* __restrict__ QbT,
    const unsigned short* __restrict__ QATTt, float* __restrict__ out) {
  int bid = blockIdx.x;
  int b = bid >> 4;
  int tm = (bid >> 1) & 7;
  int tn = bid & 1;
  const unsigned short* A  = P2Q + ((size_t)b * PLEN + tm * 128) * QLEN;
  const unsigned short* B1 = QbT + ((size_t)b * DIM + tn * 128) * QLEN;
  const unsigned short* B2 = QATTt + ((size_t)b * DIM + tn * 128) * QLEN;
  __shared__ __align__(16) unsigned short As[2][128][40];
  __shared__ __align__(16) unsigned short Bq[2][128][40];
  __shared__ __align__(16) unsigned short Bc[2][128][40];
  int t = threadIdx.x, lane = t & 63, wid = t >> 6;
  int wm = wid >> 2, wn = wid & 3;       // wave = 64 p x 32 d
  f32x4 acc1[4][2] = {}, acc2[4][2] = {};
  int r = t >> 2, c = (t & 3) * 8;
  int4 rav, rb1, rb2;
  rav = *(const int4*)&A[(size_t)r * QLEN + c];
  rb1 = *(const int4*)&B1[(size_t)r * QLEN + c];
  rb2 = *(const int4*)&B2[(size_t)r * QLEN + c];
  *(int4*)&As[0][r][c] = rav;
  *(int4*)&Bq[0][r][c] = rb1;
  *(int4*)&Bc[0][r][c] = rb2;
  __syncthreads();
  int cur = 0;
  for (int ki = 0; ki < 8; ++ki) {
    if (ki < 7) {
      int kt = (ki + 1) * 32;
      rav = *(const int4*)&A[(size_t)r * QLEN + kt + c];
      rb1 = *(const int4*)&B1[(size_t)r * QLEN + kt + c];
      rb2 = *(const int4*)&B2[(size_t)r * QLEN + kt + c];
    }
    short8 af[4], b1[2], b2[2];
    for (int i = 0; i < 4; ++i)
      af[i] = *(const short8*)&As[cur][wm * 64 + i * 16 + (lane & 15)][(lane >> 4) * 8];
    for (int j = 0; j < 2; ++j) {
      b1[j] = *(const short8*)&Bq[cur][wn * 32 + j * 16 + (lane & 15)][(lane >> 4) * 8];
      b2[j] = *(const short8*)&Bc[cur][wn * 32 + j * 16 + (lane & 15)][(lane >> 4) * 8];
    }
    for (int i = 0; i < 4; ++i)
      for (int j = 0; j < 2; ++j) {
        acc1[i][j] = __builtin_amdgcn_mfma_f32_16x16x32_bf16(af[i], b1[j], acc1[i][j], 0, 0, 0);
        acc2[i][j] = __builtin_amdgcn_mfma_f32_16x16x32_bf16(af[i], b2[j], acc2[i][j], 0, 0, 0);
      }
    if (ki < 7) {
      int nxt = cur ^ 1;
      *(int4*)&As[nxt][r][c] = rav;
      *(int4*)&Bq[nxt][r][c] = rb1;
      *(int4*)&Bc[nxt][r][c] = rb2;
      cur = nxt;
    }
    __syncthreads();
  }
  float* out1 = out;
  float* out2 = out + (size_t)NB * PLEN * DIM;
  int p0 = tm * 128 + wm * 64, d0 = tn * 128 + wn * 32;
  for (int i = 0; i < 4; ++i)
    for (int rr = 0; rr < 4; ++rr) {
      int p = p0 + i * 16 + (lane >> 4) * 4 + rr;
      size_t rowo = ((size_t)b * PLEN + p) * DIM;
      for (int j = 0; j < 2; ++j) {
        int d = d0 + j * 16 + (lane & 15);
        out1[rowo + d] = acc1[i][j][rr];
        out2[rowo + d] = acc2[i][j][rr];
      }
    }
}

extern "C" void kernel_launch(void* const* d_in, const int* in_sizes, int n_in,
                              void* d_out, int out_size, void* d_ws, size_t ws_size,
                              hipStream_t stream) {
  const float* passage  = (const float*)d_in[0];
  const float* question = (const float*)d_in[1];
  const int*   pmask    = (const int*)d_in[2];
  const int*   qmask    = (const int*)d_in[3];
  const float* W        = (const float*)d_in[4];
  const float* bias     = (const float*)d_in[5];
  float* out = (float*)d_out;

  const size_t NS = (size_t)NB * PLEN * QLEN;    // 4,194,304
  const size_t NQ = (size_t)NB * QLEN * DIM;     // 1,048,576
  char* w = (char*)d_ws;
  unsigned short* Pw   = (unsigned short*)w; w += NS * 2;
  unsigned short* Qb   = (unsigned short*)w; w += NQ * 2;
  unsigned short* PbT  = (unsigned short*)w; w += NS * 2;
  unsigned short* QbT  = (unsigned short*)w; w += NQ * 2;
  unsigned short* P2Q  = (unsigned short*)w; w += NS * 2;
  unsigned short* P2Qt = (unsigned short*)w; w += NS * 2;
  unsigned short* QATTt = (unsigned short*)w; w += NQ * 2;
  float* CM = (float*)w;                     w += (size_t)NB * 16 * QLEN * 4;
  float* CL = (float*)w;                     w += (size_t)NB * 16 * QLEN * 4;
  float* RM = (float*)w;                     w += (size_t)NB * PLEN * 4;
  float* RL = (float*)w;                     w += (size_t)NB * PLEN * 4;
  float* sp = (float*)w;                     w += (size_t)NB * PLEN * 4;
  float* sq = (float*)w;

  k_prep2<<<dim3(NB * 16 + NB * 4), dim3(256), 0, stream>>>(
      passage, question, W, Pw, Qb, PbT, QbT, sp, sq);
  k_scoreA<<<dim3(NB * 16), dim3(1024), 0, stream>>>(
      Pw, Qb, sp, sq, pmask, qmask, bias, CM, CL, RM, RL, P2Q, P2Qt);
  k_qatt2<<<dim3(NB * 16), dim3(512), 0, stream>>>(
      P2Qt, PbT, RM, RL, CM, CL, QATTt);
  k_gemm_final<<<dim3(NB * 16), dim3(512), 0, stream>>>(
      P2Q, QbT, QATTt, out);
}

// Round 12
// 64.133 us; speedup vs baseline: 1.4503x; 1.1629x over previous
//
#include <hip/hip_runtime.h>
#include <math.h>

#define NB 16
#define PLEN 1024
#define QLEN 256
#define DIM 256
#define MASKV -10000000.0f

typedef __attribute__((ext_vector_type(8))) short short8;
typedef __attribute__((ext_vector_type(4))) float f32x4;

union u4x16 { unsigned short u[4]; int2 v; };
union u8x16 { unsigned short u[8]; int4 v; };

__device__ inline unsigned short f2bf(float x) {
  unsigned int u = __float_as_uint(x);
  u += 0x7FFF + ((u >> 16) & 1);          // round-to-nearest-even
  return (unsigned short)(u >> 16);
}
__device__ inline float bf2f(unsigned short u) {
  return __uint_as_float(((unsigned int)u) << 16);
}

// ---------------- k_prepQ: question-only prep (grid NB*4).
// Qb = bf16(question), QbT transposed, sq = question . w_q
__global__ __launch_bounds__(256) void k_prepQ(
    const float* __restrict__ question, const float* __restrict__ W,
    unsigned short* __restrict__ Qb, unsigned short* __restrict__ QbT,
    float* __restrict__ sq) {
  int bid = blockIdx.x;
  int t = threadIdx.x;
  __shared__ unsigned short T[64][268];
  int b = bid >> 2, r0 = (bid & 3) * 64;
  const float* src = question + ((size_t)b * QLEN + r0) * DIM;
  unsigned short* cast_out = Qb + ((size_t)b * QLEN + r0) * DIM;
  unsigned short* tdst = QbT + (size_t)b * DIM * QLEN;
  float* dots = sq + b * QLEN + r0;
  const float* wd = W + DIM;
  int row = t >> 2, c0 = (t & 3) * 64;
  float s = 0.f;
  for (int i = 0; i < 16; ++i) {
    int d = c0 + i * 4;
    float4 x = *(const float4*)&src[(size_t)row * DIM + d];
    s += x.x * wd[d] + x.y * wd[d + 1] + x.z * wd[d + 2] + x.w * wd[d + 3];
    u4x16 tv;
    tv.u[0] = f2bf(x.x); tv.u[1] = f2bf(x.y); tv.u[2] = f2bf(x.z); tv.u[3] = f2bf(x.w);
    *(int2*)&T[row][d] = tv.v;
    *(int2*)&cast_out[(size_t)row * DIM + d] = tv.v;
  }
  s += __shfl_xor(s, 1, 64);
  s += __shfl_xor(s, 2, 64);
  if ((t & 3) == 0) dots[row] = s;
  __syncthreads();
  for (int it = 0; it < 8; ++it) {
    int g = t + it * 256;
    int d = g >> 3, ch = g & 7;
    u8x16 o;
    for (int e = 0; e < 8; ++e) o.u[e] = T[ch * 8 + e][d];
    *(int4*)&tdst[(size_t)d * QLEN + r0 + ch * 8] = o.v;
  }
}

// ---------------- k_scoreA (grid NB*16, 1024 thr = 16 waves): 64 p-rows x 256 q.
// Inline passage prep (fp32 read, bf16 cast, sp rowdot, PbT transpose-out)
// + score GEMM + mask + col partials CM/CL + exact row softmax -> P2Q, P2Qt, RM/RL.
__global__ __launch_bounds__(1024) void k_scoreA(
    const float* __restrict__ passage, const unsigned short* __restrict__ Qb,
    const float* __restrict__ Wg, const float* __restrict__ sq,
    const int* __restrict__ pmask, const int* __restrict__ qmask,
    const float* __restrict__ bias,
    unsigned short* __restrict__ PbT,
    float* __restrict__ CM, float* __restrict__ CL,
    float* __restrict__ RM, float* __restrict__ RL,
    unsigned short* __restrict__ P2Q, unsigned short* __restrict__ P2Qt) {
  int bid = blockIdx.x;
  int b = bid >> 4;
  int tile = bid & 15;
  int p0 = tile * 64;
  int t = threadIdx.x, lane = t & 63, wv = t >> 6;   // 16 waves
  int s = wv >> 2, h = wv & 3;                        // strip 0..3 (16 rows), quarter 0..3 (64 q)
  __shared__ __align__(16) unsigned short As[2][64][40];
  __shared__ __align__(16) unsigned short Bs[2][256][40];
  __shared__ __align__(16) unsigned short Pl[64][264];   // raw passage bf16, then P
  __shared__ float redM[4][256], redL[4][256];
  __shared__ float rowM[64][4], rowL[64][4];
  __shared__ float spS[64];

  int rb = t >> 2, cb = (t & 3) * 8;     // Bs staging
  int pr = t >> 4, pc = (t & 15) * 2;    // passage fp32 load: row, col-pair

  const float* psrc = passage + ((size_t)b * PLEN + p0 + pr) * DIM;

  // ---- phase 1: inline-prep + score GEMM (64 x 256, K = 256), dbuf
  f32x4 acc[4] = {};
  float spp = 0.f;
  int4 rbv = *(const int4*)&Qb[((size_t)b * QLEN + rb) * DIM + cb];
  float2 xv = *(const float2*)(psrc + pc);
  {
    spp += xv.x * Wg[pc] + xv.y * Wg[pc + 1];
    unsigned int raw = (unsigned int)f2bf(xv.x) | (((unsigned int)f2bf(xv.y)) << 16);
    unsigned int wgt = (unsigned int)f2bf(xv.x * Wg[2 * DIM + pc])
                     | (((unsigned int)f2bf(xv.y * Wg[2 * DIM + pc + 1])) << 16);
    *(unsigned int*)&Pl[pr][pc] = raw;
    *(unsigned int*)&As[0][pr][pc] = wgt;
    *(int4*)&Bs[0][rb][cb] = rbv;
  }
  __syncthreads();
  int cur = 0;
  for (int ki = 0; ki < 8; ++ki) {
    float2 xn; int4 rbn;
    if (ki < 7) {
      int kt = (ki + 1) * 32;
      rbn = *(const int4*)&Qb[((size_t)b * QLEN + rb) * DIM + kt + cb];
      xn = *(const float2*)(psrc + kt + pc);
    }
    short8 af = *(const short8*)&As[cur][s * 16 + (lane & 15)][(lane >> 4) * 8];
    for (int j = 0; j < 4; ++j) {
      short8 bf = *(const short8*)&Bs[cur][h * 64 + j * 16 + (lane & 15)][(lane >> 4) * 8];
      acc[j] = __builtin_amdgcn_mfma_f32_16x16x32_bf16(af, bf, acc[j], 0, 0, 0);
    }
    if (ki < 7) {
      int kt = (ki + 1) * 32;
      int d = kt + pc;
      spp += xn.x * Wg[d] + xn.y * Wg[d + 1];
      unsigned int raw = (unsigned int)f2bf(xn.x) | (((unsigned int)f2bf(xn.y)) << 16);
      unsigned int wgt = (unsigned int)f2bf(xn.x * Wg[2 * DIM + d])
                       | (((unsigned int)f2bf(xn.y * Wg[2 * DIM + d + 1])) << 16);
      int nxt = cur ^ 1;
      *(unsigned int*)&Pl[pr][d] = raw;
      *(unsigned int*)&As[nxt][pr][pc] = wgt;
      *(int4*)&Bs[nxt][rb][cb] = rbn;
      cur = nxt;
    }
    __syncthreads();
  }

  // ---- sp reduce (over 16-lane groups) + PbT transpose-out from Pl
  spp += __shfl_xor(spp, 1, 64);
  spp += __shfl_xor(spp, 2, 64);
  spp += __shfl_xor(spp, 4, 64);
  spp += __shfl_xor(spp, 8, 64);
  if ((t & 15) == 0) spS[pr] = spp;
  {
    int d = t >> 2, ch = t & 3;
    union { unsigned short u[16]; int4 v[2]; } o;
    for (int e = 0; e < 16; ++e) o.u[e] = Pl[ch * 16 + e][d];
    unsigned short* dst = PbT + ((size_t)b * DIM + d) * PLEN + p0 + ch * 16;
    *(int4*)dst = o.v[0];
    *(int4*)(dst + 8) = o.v[1];
  }
  __syncthreads();

  // ---- phase 2: bias + mask epilogue (registers only)
  float b0 = bias[0];
  int prow[4]; float spv[4]; int pmv[4];
  for (int r = 0; r < 4; ++r) {
    int rl = s * 16 + (lane >> 4) * 4 + r;
    prow[r] = p0 + rl;
    spv[r] = spS[rl] + b0;
    pmv[r] = pmask[b * PLEN + prow[r]];
  }
  float sqv[4]; int qmv[4];
  for (int j = 0; j < 4; ++j) {
    int q = h * 64 + j * 16 + (lane & 15);
    sqv[j] = sq[b * QLEN + q];
    qmv[j] = qmask[b * QLEN + q];
  }
  for (int j = 0; j < 4; ++j)
    for (int r = 0; r < 4; ++r) {
      float v = acc[j][r] + spv[r] + sqv[j];
      if (pmv[r] | qmv[j]) v = MASKV;
      acc[j][r] = v;
    }

  // ---- phase 3a: column partials (per strip) + row partials (per quarter)
  for (int j = 0; j < 4; ++j) {
    float m = fmaxf(fmaxf(acc[j][0], acc[j][1]), fmaxf(acc[j][2], acc[j][3]));
    m = fmaxf(m, __shfl_xor(m, 16, 64));
    m = fmaxf(m, __shfl_xor(m, 32, 64));
    float e = 0.f;
    for (int r = 0; r < 4; ++r) e += __expf(acc[j][r] - m);
    e += __shfl_xor(e, 16, 64);
    e += __shfl_xor(e, 32, 64);
    if ((lane >> 4) == 0) {
      redM[s][h * 64 + j * 16 + (lane & 15)] = m;
      redL[s][h * 64 + j * 16 + (lane & 15)] = e;
    }
  }
  for (int r = 0; r < 4; ++r) {
    int rl = s * 16 + (lane >> 4) * 4 + r;
    float m = acc[0][r];
    for (int j = 1; j < 4; ++j) m = fmaxf(m, acc[j][r]);
    for (int msk = 1; msk <= 8; msk <<= 1) m = fmaxf(m, __shfl_xor(m, msk, 64));
    float l = 0.f;
    for (int j = 0; j < 4; ++j) l += __expf(acc[j][r] - m);
    for (int msk = 1; msk <= 8; msk <<= 1) l += __shfl_xor(l, msk, 64);
    if ((lane & 15) == 0) { rowM[rl][h] = m; rowL[rl][h] = l; }
  }
  __syncthreads();

  // ---- phase 3b: CM/CL store (combine 4 strips)
  if (t < 256) {
    int q = t;
    float M = fmaxf(fmaxf(redM[0][q], redM[1][q]), fmaxf(redM[2][q], redM[3][q]));
    float L = redL[0][q] * __expf(redM[0][q] - M) + redL[1][q] * __expf(redM[1][q] - M)
            + redL[2][q] * __expf(redM[2][q] - M) + redL[3][q] * __expf(redM[3][q] - M);
    size_t o = ((size_t)b * 16 + tile) * QLEN + q;
    CM[o] = M; CL[o] = L;
  }

  // ---- phase 4: exact row softmax (combine 4 quarters) -> Pl (bf16) + RM/RL
  for (int r = 0; r < 4; ++r) {
    int rl = s * 16 + (lane >> 4) * 4 + r;
    float m0 = rowM[rl][0], m1 = rowM[rl][1], m2 = rowM[rl][2], m3 = rowM[rl][3];
    float m = fmaxf(fmaxf(m0, m1), fmaxf(m2, m3));
    float l = rowL[rl][0] * __expf(m0 - m) + rowL[rl][1] * __expf(m1 - m)
            + rowL[rl][2] * __expf(m2 - m) + rowL[rl][3] * __expf(m3 - m);
    if (h == 0 && (lane & 15) == 0) {
      RM[(size_t)b * PLEN + p0 + rl] = m;
      RL[(size_t)b * PLEN + p0 + rl] = l;
    }
    float inv = 1.0f / l;
    for (int j = 0; j < 4; ++j) {
      float e = (pmv[r] | qmv[j]) ? 0.0f : __expf(acc[j][r] - m) * inv;
      Pl[rl][h * 64 + j * 16 + (lane & 15)] = f2bf(e);
    }
  }
  __syncthreads();

  // ---- P2Q row-major store (coalesced from Pl)
  for (int k = 0; k < 2; ++k) {
    int idx = t + k * 1024;
    int row = idx >> 5, c8 = idx & 31;
    *(int4*)&P2Q[((size_t)b * PLEN + p0 + row) * QLEN + c8 * 8] = *(const int4*)&Pl[row][c8 * 8];
  }
  // ---- P2Qt transposed store
  {
    int q = t >> 2, pcc = t & 3;
    union { unsigned short u[16]; int4 v[2]; } o;
    for (int e = 0; e < 16; ++e) o.u[e] = Pl[pcc * 16 + e][q];
    unsigned short* dst = P2Qt + ((size_t)b * QLEN + q) * PLEN + p0 + pcc * 16;
    *(int4*)dst = o.v[0];
    *(int4*)(dst + 8) = o.v[1];
  }
}

// ---------------- k_qatt2 (512 thr, 8 waves): fused col-softmax + GEMM.
//   W2[p,q] = P2Q[p,q] * RL[p] * exp(RM[p] - Mq) * iLq   (computed on the fly)
//   QATTt[b,d,q] = sum_p PbT[d,p] * W2[p,q]
__global__ __launch_bounds__(512) void k_qatt2(
    const unsigned short* __restrict__ P2Qt, const unsigned short* __restrict__ PbT,
    const float* __restrict__ RM, const float* __restrict__ RL,
    const float* __restrict__ CM, const float* __restrict__ CL,
    unsigned short* __restrict__ QATTt) {
  int bid = blockIdx.x;
  int b = bid >> 4, dt = (bid >> 2) & 3, qt = bid & 3;
  int t = threadIdx.x, lane = t & 63, wid = t >> 6;
  int wm = wid >> 2, wn = wid & 3;                 // wave = 32 d x 16 q
  __shared__ __align__(16) unsigned short Wt[64][72];
  __shared__ __align__(16) unsigned short At[64][72];
  __shared__ float MqS[64], iLqS[64];
  if (t < 64) {
    int q = qt * 64 + t;
    float M = CM[((size_t)b * 16) * QLEN + q];
    for (int tm = 1; tm < 16; ++tm)
      M = fmaxf(M, CM[((size_t)b * 16 + tm) * QLEN + q]);
    float L = 0.f;
    for (int tm = 0; tm < 16; ++tm) {
      size_t o = ((size_t)b * 16 + tm) * QLEN + q;
      L += CL[o] * __expf(CM[o] - M);
    }
    MqS[t] = (M < -1.0e6f) ? 1.0e30f : M;          // masked column -> exp() == 0
    iLqS[t] = 1.0f / L;
  }
  __syncthreads();

  int rrow = t >> 3;            // 0..63: q-row for Wt, d-row for At
  int pch = (t & 7) * 8;        // p-chunk within 64-p slice
  const unsigned short* Wsrc = P2Qt + ((size_t)b * QLEN + qt * 64 + rrow) * PLEN + pch;
  const unsigned short* Asrc = PbT + ((size_t)b * DIM + dt * 64 + rrow) * PLEN + pch;
  const float* rmB = RM + (size_t)b * PLEN + pch;
  const float* rlB = RL + (size_t)b * PLEN + pch;
  float Mq = MqS[rrow], giL = iLqS[rrow];

  f32x4 acc[2] = {};
  int4 wv = *(const int4*)Wsrc;
  int4 av = *(const int4*)Asrc;
  float4 rm0 = *(const float4*)rmB, rm1 = *(const float4*)(rmB + 4);
  float4 rl0 = *(const float4*)rlB, rl1 = *(const float4*)(rlB + 4);

  for (int ps = 0; ps < 16; ++ps) {
    float rmv[8] = {rm0.x, rm0.y, rm0.z, rm0.w, rm1.x, rm1.y, rm1.z, rm1.w};
    float rlv[8] = {rl0.x, rl0.y, rl0.z, rl0.w, rl1.x, rl1.y, rl1.z, rl1.w};
    const unsigned short* wu = (const unsigned short*)&wv;
    u8x16 wo;
#pragma unroll
    for (int e = 0; e < 8; ++e) {
      float w = bf2f(wu[e]) * rlv[e] * __expf(rmv[e] - Mq) * giL;
      wo.u[e] = f2bf(w);
    }
    *(int4*)&Wt[rrow][pch] = wo.v;
    *(int4*)&At[rrow][pch] = av;
    if (ps < 15) {
      int off = (ps + 1) * 64;
      wv = *(const int4*)(Wsrc + off);
      av = *(const int4*)(Asrc + off);
      rm0 = *(const float4*)(rmB + off); rm1 = *(const float4*)(rmB + off + 4);
      rl0 = *(const float4*)(rlB + off); rl1 = *(const float4*)(rlB + off + 4);
    }
    __syncthreads();
    for (int kk = 0; kk < 64; kk += 32) {
      short8 bf = *(const short8*)&Wt[wn * 16 + (lane & 15)][kk + (lane >> 4) * 8];
      for (int i = 0; i < 2; ++i) {
        short8 af = *(const short8*)&At[wm * 32 + i * 16 + (lane & 15)][kk + (lane >> 4) * 8];
        acc[i] = __builtin_amdgcn_mfma_f32_16x16x32_bf16(af, bf, acc[i], 0, 0, 0);
      }
    }
    __syncthreads();
  }
  int d0 = dt * 64 + wm * 32, q0 = qt * 64 + wn * 16;
  for (int i = 0; i < 2; ++i)
    for (int rr = 0; rr < 4; ++rr) {
      int d = d0 + i * 16 + (lane >> 4) * 4 + rr;
      QATTt[((size_t)b * DIM + d) * QLEN + q0 + (lane & 15)] = f2bf(acc[i][rr]);
    }
}

// ---------------- k_gemm_final (512 thr, 8 waves): shared-A dual-B
//   out1 = P2Q @ QbT^T ; out2 = P2Q @ QATTt^T ; 128p x 128d per block, dbuf
__global__ __launch_bounds__(512) void k_gemm_final(
    const unsigned short* __restrict__ P2Q, const unsigned short* __restrict__ QbT,
    const unsigned short* __restrict__ QATTt, float* __restrict__ out) {
  int bid = blockIdx.x;
  int b = bid >> 4;
  int tm = (bid >> 1) & 7;
  int tn = bid & 1;
  const unsigned short* A  = P2Q + ((size_t)b * PLEN + tm * 128) * QLEN;
  const unsigned short* B1 = QbT + ((size_t)b * DIM + tn * 128) * QLEN;
  const unsigned short* B2 = QATTt + ((size_t)b * DIM + tn * 128) * QLEN;
  __shared__ __align__(16) unsigned short As[2][128][40];
  __shared__ __align__(16) unsigned short Bq[2][128][40];
  __shared__ __align__(16) unsigned short Bc[2][128][40];
  int t = threadIdx.x, lane = t & 63, wid = t >> 6;
  int wm = wid >> 2, wn = wid & 3;       // wave = 64 p x 32 d
  f32x4 acc1[4][2] = {}, acc2[4][2] = {};
  int r = t >> 2, c = (t & 3) * 8;
  int4 rav, rb1, rb2;
  rav = *(const int4*)&A[(size_t)r * QLEN + c];
  rb1 = *(const int4*)&B1[(size_t)r * QLEN + c];
  rb2 = *(const int4*)&B2[(size_t)r * QLEN + c];
  *(int4*)&As[0][r][c] = rav;
  *(int4*)&Bq[0][r][c] = rb1;
  *(int4*)&Bc[0][r][c] = rb2;
  __syncthreads();
  int cur = 0;
  for (int ki = 0; ki < 8; ++ki) {
    if (ki < 7) {
      int kt = (ki + 1) * 32;
      rav = *(const int4*)&A[(size_t)r * QLEN + kt + c];
      rb1 = *(const int4*)&B1[(size_t)r * QLEN + kt + c];
      rb2 = *(const int4*)&B2[(size_t)r * QLEN + kt + c];
    }
    short8 af[4], b1[2], b2[2];
    for (int i = 0; i < 4; ++i)
      af[i] = *(const short8*)&As[cur][wm * 64 + i * 16 + (lane & 15)][(lane >> 4) * 8];
    for (int j = 0; j < 2; ++j) {
      b1[j] = *(const short8*)&Bq[cur][wn * 32 + j * 16 + (lane & 15)][(lane >> 4) * 8];
      b2[j] = *(const short8*)&Bc[cur][wn * 32 + j * 16 + (lane & 15)][(lane >> 4) * 8];
    }
    for (int i = 0; i < 4; ++i)
      for (int j = 0; j < 2; ++j) {
        acc1[i][j] = __builtin_amdgcn_mfma_f32_16x16x32_bf16(af[i], b1[j], acc1[i][j], 0, 0, 0);
        acc2[i][j] = __builtin_amdgcn_mfma_f32_16x16x32_bf16(af[i], b2[j], acc2[i][j], 0, 0, 0);
      }
    if (ki < 7) {
      int nxt = cur ^ 1;
      *(int4*)&As[nxt][r][c] = rav;
      *(int4*)&Bq[nxt][r][c] = rb1;
      *(int4*)&Bc[nxt][r][c] = rb2;
      cur = nxt;
    }
    __syncthreads();
  }
  float* out1 = out;
  float* out2 = out + (size_t)NB * PLEN * DIM;
  int p0 = tm * 128 + wm * 64, d0 = tn * 128 + wn * 32;
  for (int i = 0; i < 4; ++i)
    for (int rr = 0; rr < 4; ++rr) {
      int p = p0 + i * 16 + (lane >> 4) * 4 + rr;
      size_t rowo = ((size_t)b * PLEN + p) * DIM;
      for (int j = 0; j < 2; ++j) {
        int d = d0 + j * 16 + (lane & 15);
        out1[rowo + d] = acc1[i][j][rr];
        out2[rowo + d] = acc2[i][j][rr];
      }
    }
}

extern "C" void kernel_launch(void* const* d_in, const int* in_sizes, int n_in,
                              void* d_out, int out_size, void* d_ws, size_t ws_size,
                              hipStream_t stream) {
  const float* passage  = (const float*)d_in[0];
  const float* question = (const float*)d_in[1];
  const int*   pmask    = (const int*)d_in[2];
  const int*   qmask    = (const int*)d_in[3];
  const float* W        = (const float*)d_in[4];
  const float* bias     = (const float*)d_in[5];
  float* out = (float*)d_out;

  const size_t NS = (size_t)NB * PLEN * QLEN;    // 4,194,304
  const size_t NQ = (size_t)NB * QLEN * DIM;     // 1,048,576
  char* w = (char*)d_ws;
  unsigned short* Qb   = (unsigned short*)w; w += NQ * 2;
  unsigned short* PbT  = (unsigned short*)w; w += NS * 2;
  unsigned short* QbT  = (unsigned short*)w; w += NQ * 2;
  unsigned short* P2Q  = (unsigned short*)w; w += NS * 2;
  unsigned short* P2Qt = (unsigned short*)w; w += NS * 2;
  unsigned short* QATTt = (unsigned short*)w; w += NQ * 2;
  float* CM = (float*)w;                     w += (size_t)NB * 16 * QLEN * 4;
  float* CL = (float*)w;                     w += (size_t)NB * 16 * QLEN * 4;
  float* RM = (float*)w;                     w += (size_t)NB * PLEN * 4;
  float* RL = (float*)w;                     w += (size_t)NB * PLEN * 4;
  float* sq = (float*)w;

  k_prepQ<<<dim3(NB * 4), dim3(256), 0, stream>>>(
      question, W, Qb, QbT, sq);
  k_scoreA<<<dim3(NB * 16), dim3(1024), 0, stream>>>(
      passage, Qb, W, sq, pmask, qmask, bias, PbT, CM, CL, RM, RL, P2Q, P2Qt);
  k_qatt2<<<dim3(NB * 16), dim3(512), 0, stream>>>(
      P2Qt, PbT, RM, RL, CM, CL, QATTt);
  k_gemm_final<<<dim3(NB * 16), dim3(512), 0, stream>>>(
      P2Q, QbT, QATTt, out);
}

// Round 13
// 61.552 us; speedup vs baseline: 1.5112x; 1.0419x over previous
//
#include <hip/hip_runtime.h>
#include <math.h>

#define NB 16
#define PLEN 1024
#define QLEN 256
#define DIM 256
#define MASKV -10000000.0f

typedef __attribute__((ext_vector_type(8))) short short8;
typedef __attribute__((ext_vector_type(4))) float f32x4;

union u4x16 { unsigned short u[4]; int2 v; };
union u8x16 { unsigned short u[8]; int4 v; };

__device__ inline unsigned short f2bf(float x) {
  unsigned int u = __float_as_uint(x);
  u += 0x7FFF + ((u >> 16) & 1);          // round-to-nearest-even
  return (unsigned short)(u >> 16);
}
__device__ inline float bf2f(unsigned short u) {
  return __uint_as_float(((unsigned int)u) << 16);
}

// ---------------- k_prepQ: question-only prep (grid NB*4).
__global__ __launch_bounds__(256) void k_prepQ(
    const float* __restrict__ question, const float* __restrict__ W,
    unsigned short* __restrict__ Qb, unsigned short* __restrict__ QbT,
    float* __restrict__ sq) {
  int bid = blockIdx.x;
  int t = threadIdx.x;
  __shared__ unsigned short T[64][268];
  int b = bid >> 2, r0 = (bid & 3) * 64;
  const float* src = question + ((size_t)b * QLEN + r0) * DIM;
  unsigned short* cast_out = Qb + ((size_t)b * QLEN + r0) * DIM;
  unsigned short* tdst = QbT + (size_t)b * DIM * QLEN;
  float* dots = sq + b * QLEN + r0;
  const float* wd = W + DIM;
  int row = t >> 2, c0 = (t & 3) * 64;
  float s = 0.f;
  for (int i = 0; i < 16; ++i) {
    int d = c0 + i * 4;
    float4 x = *(const float4*)&src[(size_t)row * DIM + d];
    s += x.x * wd[d] + x.y * wd[d + 1] + x.z * wd[d + 2] + x.w * wd[d + 3];
    u4x16 tv;
    tv.u[0] = f2bf(x.x); tv.u[1] = f2bf(x.y); tv.u[2] = f2bf(x.z); tv.u[3] = f2bf(x.w);
    *(int2*)&T[row][d] = tv.v;
    *(int2*)&cast_out[(size_t)row * DIM + d] = tv.v;
  }
  s += __shfl_xor(s, 1, 64);
  s += __shfl_xor(s, 2, 64);
  if ((t & 3) == 0) dots[row] = s;
  __syncthreads();
  for (int it = 0; it < 8; ++it) {
    int g = t + it * 256;
    int d = g >> 3, ch = g & 7;
    u8x16 o;
    for (int e = 0; e < 8; ++e) o.u[e] = T[ch * 8 + e][d];
    *(int4*)&tdst[(size_t)d * QLEN + r0 + ch * 8] = o.v;
  }
}

// ---------------- k_scoreA (grid NB*16, 1024 thr = 16 waves): 64 p-rows x 256 q.
// Inline passage prep + score GEMM + mask + col partials + exact row softmax.
// XCD-swizzled block mapping for Qb-panel L2 locality.
__global__ __launch_bounds__(1024) void k_scoreA(
    const float* __restrict__ passage, const unsigned short* __restrict__ Qb,
    const float* __restrict__ Wg, const float* __restrict__ sq,
    const int* __restrict__ pmask, const int* __restrict__ qmask,
    const float* __restrict__ bias,
    unsigned short* __restrict__ PbT,
    float* __restrict__ CM, float* __restrict__ CL,
    float* __restrict__ RM, float* __restrict__ RL,
    unsigned short* __restrict__ P2Q, unsigned short* __restrict__ P2Qt) {
  int bid0 = blockIdx.x;
  int bid = (bid0 & 7) * 32 + (bid0 >> 3);           // XCD swizzle (256 = 8 * 32, bijective)
  int b = bid >> 4;
  int tile = bid & 15;
  int p0 = tile * 64;
  int t = threadIdx.x, lane = t & 63, wv = t >> 6;   // 16 waves
  int s = wv >> 2, h = wv & 3;
  __shared__ __align__(16) unsigned short As[2][64][40];
  __shared__ __align__(16) unsigned short Bs[2][256][40];
  __shared__ __align__(16) unsigned short Pl[64][264];
  __shared__ float redM[4][256], redL[4][256];
  __shared__ float rowM[64][4], rowL[64][4];
  __shared__ float spS[64];

  int rb = t >> 2, cb = (t & 3) * 8;
  int pr = t >> 4, pc = (t & 15) * 2;
  const float* psrc = passage + ((size_t)b * PLEN + p0 + pr) * DIM;

  // ---- phase 1: inline-prep + score GEMM (64 x 256, K = 256), dbuf
  f32x4 acc[4] = {};
  float spp = 0.f;
  int4 rbv = *(const int4*)&Qb[((size_t)b * QLEN + rb) * DIM + cb];
  float2 xv = *(const float2*)(psrc + pc);
  {
    spp += xv.x * Wg[pc] + xv.y * Wg[pc + 1];
    unsigned int raw = (unsigned int)f2bf(xv.x) | (((unsigned int)f2bf(xv.y)) << 16);
    unsigned int wgt = (unsigned int)f2bf(xv.x * Wg[2 * DIM + pc])
                     | (((unsigned int)f2bf(xv.y * Wg[2 * DIM + pc + 1])) << 16);
    *(unsigned int*)&Pl[pr][pc] = raw;
    *(unsigned int*)&As[0][pr][pc] = wgt;
    *(int4*)&Bs[0][rb][cb] = rbv;
  }
  __syncthreads();
  int cur = 0;
  for (int ki = 0; ki < 8; ++ki) {
    float2 xn; int4 rbn;
    if (ki < 7) {
      int kt = (ki + 1) * 32;
      rbn = *(const int4*)&Qb[((size_t)b * QLEN + rb) * DIM + kt + cb];
      xn = *(const float2*)(psrc + kt + pc);
    }
    short8 af = *(const short8*)&As[cur][s * 16 + (lane & 15)][(lane >> 4) * 8];
    for (int j = 0; j < 4; ++j) {
      short8 bf = *(const short8*)&Bs[cur][h * 64 + j * 16 + (lane & 15)][(lane >> 4) * 8];
      acc[j] = __builtin_amdgcn_mfma_f32_16x16x32_bf16(af, bf, acc[j], 0, 0, 0);
    }
    if (ki < 7) {
      int kt = (ki + 1) * 32;
      int d = kt + pc;
      spp += xn.x * Wg[d] + xn.y * Wg[d + 1];
      unsigned int raw = (unsigned int)f2bf(xn.x) | (((unsigned int)f2bf(xn.y)) << 16);
      unsigned int wgt = (unsigned int)f2bf(xn.x * Wg[2 * DIM + d])
                       | (((unsigned int)f2bf(xn.y * Wg[2 * DIM + d + 1])) << 16);
      int nxt = cur ^ 1;
      *(unsigned int*)&Pl[pr][d] = raw;
      *(unsigned int*)&As[nxt][pr][pc] = wgt;
      *(int4*)&Bs[nxt][rb][cb] = rbn;
      cur = nxt;
    }
    __syncthreads();
  }

  // ---- sp reduce + PbT transpose-out from Pl
  spp += __shfl_xor(spp, 1, 64);
  spp += __shfl_xor(spp, 2, 64);
  spp += __shfl_xor(spp, 4, 64);
  spp += __shfl_xor(spp, 8, 64);
  if ((t & 15) == 0) spS[pr] = spp;
  {
    int d = t >> 2, ch = t & 3;
    union { unsigned short u[16]; int4 v[2]; } o;
    for (int e = 0; e < 16; ++e) o.u[e] = Pl[ch * 16 + e][d];
    unsigned short* dst = PbT + ((size_t)b * DIM + d) * PLEN + p0 + ch * 16;
    *(int4*)dst = o.v[0];
    *(int4*)(dst + 8) = o.v[1];
  }
  __syncthreads();

  // ---- phase 2: bias + mask epilogue
  float b0 = bias[0];
  int prow[4]; float spv[4]; int pmv[4];
  for (int r = 0; r < 4; ++r) {
    int rl = s * 16 + (lane >> 4) * 4 + r;
    prow[r] = p0 + rl;
    spv[r] = spS[rl] + b0;
    pmv[r] = pmask[b * PLEN + prow[r]];
  }
  float sqv[4]; int qmv[4];
  for (int j = 0; j < 4; ++j) {
    int q = h * 64 + j * 16 + (lane & 15);
    sqv[j] = sq[b * QLEN + q];
    qmv[j] = qmask[b * QLEN + q];
  }
  for (int j = 0; j < 4; ++j)
    for (int r = 0; r < 4; ++r) {
      float v = acc[j][r] + spv[r] + sqv[j];
      if (pmv[r] | qmv[j]) v = MASKV;
      acc[j][r] = v;
    }

  // ---- phase 3a: column + row partials
  for (int j = 0; j < 4; ++j) {
    float m = fmaxf(fmaxf(acc[j][0], acc[j][1]), fmaxf(acc[j][2], acc[j][3]));
    m = fmaxf(m, __shfl_xor(m, 16, 64));
    m = fmaxf(m, __shfl_xor(m, 32, 64));
    float e = 0.f;
    for (int r = 0; r < 4; ++r) e += __expf(acc[j][r] - m);
    e += __shfl_xor(e, 16, 64);
    e += __shfl_xor(e, 32, 64);
    if ((lane >> 4) == 0) {
      redM[s][h * 64 + j * 16 + (lane & 15)] = m;
      redL[s][h * 64 + j * 16 + (lane & 15)] = e;
    }
  }
  for (int r = 0; r < 4; ++r) {
    int rl = s * 16 + (lane >> 4) * 4 + r;
    float m = acc[0][r];
    for (int j = 1; j < 4; ++j) m = fmaxf(m, acc[j][r]);
    for (int msk = 1; msk <= 8; msk <<= 1) m = fmaxf(m, __shfl_xor(m, msk, 64));
    float l = 0.f;
    for (int j = 0; j < 4; ++j) l += __expf(acc[j][r] - m);
    for (int msk = 1; msk <= 8; msk <<= 1) l += __shfl_xor(l, msk, 64);
    if ((lane & 15) == 0) { rowM[rl][h] = m; rowL[rl][h] = l; }
  }
  __syncthreads();

  // ---- phase 3b: CM/CL store
  if (t < 256) {
    int q = t;
    float M = fmaxf(fmaxf(redM[0][q], redM[1][q]), fmaxf(redM[2][q], redM[3][q]));
    float L = redL[0][q] * __expf(redM[0][q] - M) + redL[1][q] * __expf(redM[1][q] - M)
            + redL[2][q] * __expf(redM[2][q] - M) + redL[3][q] * __expf(redM[3][q] - M);
    size_t o = ((size_t)b * 16 + tile) * QLEN + q;
    CM[o] = M; CL[o] = L;
  }

  // ---- phase 4: exact row softmax -> Pl (bf16) + RM/RL
  for (int r = 0; r < 4; ++r) {
    int rl = s * 16 + (lane >> 4) * 4 + r;
    float m0 = rowM[rl][0], m1 = rowM[rl][1], m2 = rowM[rl][2], m3 = rowM[rl][3];
    float m = fmaxf(fmaxf(m0, m1), fmaxf(m2, m3));
    float l = rowL[rl][0] * __expf(m0 - m) + rowL[rl][1] * __expf(m1 - m)
            + rowL[rl][2] * __expf(m2 - m) + rowL[rl][3] * __expf(m3 - m);
    if (h == 0 && (lane & 15) == 0) {
      RM[(size_t)b * PLEN + p0 + rl] = m;
      RL[(size_t)b * PLEN + p0 + rl] = l;
    }
    float inv = 1.0f / l;
    for (int j = 0; j < 4; ++j) {
      float e = (pmv[r] | qmv[j]) ? 0.0f : __expf(acc[j][r] - m) * inv;
      Pl[rl][h * 64 + j * 16 + (lane & 15)] = f2bf(e);
    }
  }
  __syncthreads();

  // ---- P2Q row-major store
  for (int k = 0; k < 2; ++k) {
    int idx = t + k * 1024;
    int row = idx >> 5, c8 = idx & 31;
    *(int4*)&P2Q[((size_t)b * PLEN + p0 + row) * QLEN + c8 * 8] = *(const int4*)&Pl[row][c8 * 8];
  }
  // ---- P2Qt transposed store
  {
    int q = t >> 2, pcc = t & 3;
    union { unsigned short u[16]; int4 v[2]; } o;
    for (int e = 0; e < 16; ++e) o.u[e] = Pl[pcc * 16 + e][q];
    unsigned short* dst = P2Qt + ((size_t)b * QLEN + q) * PLEN + p0 + pcc * 16;
    *(int4*)dst = o.v[0];
    *(int4*)(dst + 8) = o.v[1];
  }
}

// ---------------- k_mid (512 thr, grid NB*32): heterogeneous overlap.
// Blocks [0, NB*16): fused col-softmax + qatt GEMM -> QATTt.
// Blocks [NB*16, NB*32): out1 = P2Q @ QbT^T (128p x 128d tiles).
__global__ __launch_bounds__(512) void k_mid(
    const unsigned short* __restrict__ P2Qt, const unsigned short* __restrict__ PbT,
    const unsigned short* __restrict__ P2Q, const unsigned short* __restrict__ QbT,
    const float* __restrict__ RM, const float* __restrict__ RL,
    const float* __restrict__ CM, const float* __restrict__ CL,
    unsigned short* __restrict__ QATTt, float* __restrict__ out1) {
  __shared__ __align__(16) char smem[40960];
  int t = threadIdx.x, lane = t & 63, wid = t >> 6;

  if (blockIdx.x < NB * 16) {
    // ======== qatt2 ========
    int bid = blockIdx.x;
    int b = bid >> 4, dt = (bid >> 2) & 3, qt = bid & 3;
    int wm = wid >> 2, wn = wid & 3;                 // wave = 32 d x 16 q
    typedef unsigned short row72[72];
    row72* Wt = (row72*)smem;                        //  9216 B
    row72* At = (row72*)(smem + 9216);               //  9216 B
    float* MqS = (float*)(smem + 18432);
    float* iLqS = (float*)(smem + 18688);
    if (t < 64) {
      int q = qt * 64 + t;
      float M = CM[((size_t)b * 16) * QLEN + q];
      for (int tm = 1; tm < 16; ++tm)
        M = fmaxf(M, CM[((size_t)b * 16 + tm) * QLEN + q]);
      float L = 0.f;
      for (int tm = 0; tm < 16; ++tm) {
        size_t o = ((size_t)b * 16 + tm) * QLEN + q;
        L += CL[o] * __expf(CM[o] - M);
      }
      MqS[t] = (M < -1.0e6f) ? 1.0e30f : M;
      iLqS[t] = 1.0f / L;
    }
    __syncthreads();

    int rrow = t >> 3;
    int pch = (t & 7) * 8;
    const unsigned short* Wsrc = P2Qt + ((size_t)b * QLEN + qt * 64 + rrow) * PLEN + pch;
    const unsigned short* Asrc = PbT + ((size_t)b * DIM + dt * 64 + rrow) * PLEN + pch;
    const float* rmB = RM + (size_t)b * PLEN + pch;
    const float* rlB = RL + (size_t)b * PLEN + pch;
    float Mq = MqS[rrow], giL = iLqS[rrow];

    f32x4 acc[2] = {};
    int4 wvv = *(const int4*)Wsrc;
    int4 av = *(const int4*)Asrc;
    float4 rm0 = *(const float4*)rmB, rm1 = *(const float4*)(rmB + 4);
    float4 rl0 = *(const float4*)rlB, rl1 = *(const float4*)(rlB + 4);

    for (int ps = 0; ps < 16; ++ps) {
      float rmv[8] = {rm0.x, rm0.y, rm0.z, rm0.w, rm1.x, rm1.y, rm1.z, rm1.w};
      float rlv[8] = {rl0.x, rl0.y, rl0.z, rl0.w, rl1.x, rl1.y, rl1.z, rl1.w};
      const unsigned short* wu = (const unsigned short*)&wvv;
      u8x16 wo;
#pragma unroll
      for (int e = 0; e < 8; ++e) {
        float w = bf2f(wu[e]) * rlv[e] * __expf(rmv[e] - Mq) * giL;
        wo.u[e] = f2bf(w);
      }
      *(int4*)&Wt[rrow][pch] = wo.v;
      *(int4*)&At[rrow][pch] = av;
      if (ps < 15) {
        int off = (ps + 1) * 64;
        wvv = *(const int4*)(Wsrc + off);
        av = *(const int4*)(Asrc + off);
        rm0 = *(const float4*)(rmB + off); rm1 = *(const float4*)(rmB + off + 4);
        rl0 = *(const float4*)(rlB + off); rl1 = *(const float4*)(rlB + off + 4);
      }
      __syncthreads();
      for (int kk = 0; kk < 64; kk += 32) {
        short8 bf = *(const short8*)&Wt[wn * 16 + (lane & 15)][kk + (lane >> 4) * 8];
        for (int i = 0; i < 2; ++i) {
          short8 af = *(const short8*)&At[wm * 32 + i * 16 + (lane & 15)][kk + (lane >> 4) * 8];
          acc[i] = __builtin_amdgcn_mfma_f32_16x16x32_bf16(af, bf, acc[i], 0, 0, 0);
        }
      }
      __syncthreads();
    }
    int d0 = dt * 64 + wm * 32, q0 = qt * 64 + wn * 16;
    for (int i = 0; i < 2; ++i)
      for (int rr = 0; rr < 4; ++rr) {
        int d = d0 + i * 16 + (lane >> 4) * 4 + rr;
        QATTt[((size_t)b * DIM + d) * QLEN + q0 + (lane & 15)] = f2bf(acc[i][rr]);
      }
  } else {
    // ======== out1 = P2Q @ QbT^T ========
    int bid = blockIdx.x - NB * 16;
    int b = bid >> 4;
    int tm = (bid >> 1) & 7;
    int tn = bid & 1;
    const unsigned short* A  = P2Q + ((size_t)b * PLEN + tm * 128) * QLEN;
    const unsigned short* B1 = QbT + ((size_t)b * DIM + tn * 128) * QLEN;
    typedef unsigned short row40[40];
    row40* As2 = (row40*)smem;                 // 2*128*40*2 = 20480 B
    row40* Bq = (row40*)(smem + 20480);        // 20480 B
    int wm = wid >> 2, wn = wid & 3;           // wave = 64 p x 32 d
    f32x4 acc1[4][2] = {};
    int r = t >> 2, c = (t & 3) * 8;
    int4 rav = *(const int4*)&A[(size_t)r * QLEN + c];
    int4 rb1 = *(const int4*)&B1[(size_t)r * QLEN + c];
    *(int4*)&As2[r][c] = rav;
    *(int4*)&Bq[r][c] = rb1;
    __syncthreads();
    int cur = 0;
    for (int ki = 0; ki < 8; ++ki) {
      if (ki < 7) {
        int kt = (ki + 1) * 32;
        rav = *(const int4*)&A[(size_t)r * QLEN + kt + c];
        rb1 = *(const int4*)&B1[(size_t)r * QLEN + kt + c];
      }
      short8 af[4], b1v[2];
      for (int i = 0; i < 4; ++i)
        af[i] = *(const short8*)&As2[cur * 128 + wm * 64 + i * 16 + (lane & 15)][(lane >> 4) * 8];
      for (int j = 0; j < 2; ++j)
        b1v[j] = *(const short8*)&Bq[cur * 128 + wn * 32 + j * 16 + (lane & 15)][(lane >> 4) * 8];
      for (int i = 0; i < 4; ++i)
        for (int j = 0; j < 2; ++j)
          acc1[i][j] = __builtin_amdgcn_mfma_f32_16x16x32_bf16(af[i], b1v[j], acc1[i][j], 0, 0, 0);
      if (ki < 7) {
        int nxt = cur ^ 1;
        *(int4*)&As2[nxt * 128 + r][c] = rav;
        *(int4*)&Bq[nxt * 128 + r][c] = rb1;
        cur = nxt;
      }
      __syncthreads();
    }
    int p0 = tm * 128 + wm * 64, d0 = tn * 128 + wn * 32;
    for (int i = 0; i < 4; ++i)
      for (int rr = 0; rr < 4; ++rr) {
        int p = p0 + i * 16 + (lane >> 4) * 4 + rr;
        size_t rowo = ((size_t)b * PLEN + p) * DIM;
        for (int j = 0; j < 2; ++j) {
          int d = d0 + j * 16 + (lane & 15);
          out1[rowo + d] = acc1[i][j][rr];
        }
      }
  }
}

// ---------------- k_final2 (512 thr): out2 = P2Q @ QATTt^T; 128p x 128d, dbuf
__global__ __launch_bounds__(512) void k_final2(
    const unsigned short* __restrict__ P2Q, const unsigned short* __restrict__ QATTt,
    float* __restrict__ out2) {
  int bid = blockIdx.x;
  int b = bid >> 4;
  int tm = (bid >> 1) & 7;
  int tn = bid & 1;
  const unsigned short* A  = P2Q + ((size_t)b * PLEN + tm * 128) * QLEN;
  const unsigned short* B2 = QATTt + ((size_t)b * DIM + tn * 128) * QLEN;
  __shared__ __align__(16) unsigned short As[2][128][40];
  __shared__ __align__(16) unsigned short Bc[2][128][40];
  int t = threadIdx.x, lane = t & 63, wid = t >> 6;
  int wm = wid >> 2, wn = wid & 3;       // wave = 64 p x 32 d
  f32x4 acc[4][2] = {};
  int r = t >> 2, c = (t & 3) * 8;
  int4 rav = *(const int4*)&A[(size_t)r * QLEN + c];
  int4 rb2 = *(const int4*)&B2[(size_t)r * QLEN + c];
  *(int4*)&As[0][r][c] = rav;
  *(int4*)&Bc[0][r][c] = rb2;
  __syncthreads();
  int cur = 0;
  for (int ki = 0; ki < 8; ++ki) {
    if (ki < 7) {
      int kt = (ki + 1) * 32;
      rav = *(const int4*)&A[(size_t)r * QLEN + kt + c];
      rb2 = *(const int4*)&B2[(size_t)r * QLEN + kt + c];
    }
    short8 af[4], bc[2];
    for (int i = 0; i < 4; ++i)
      af[i] = *(const short8*)&As[cur][wm * 64 + i * 16 + (lane & 15)][(lane >> 4) * 8];
    for (int j = 0; j < 2; ++j)
      bc[j] = *(const short8*)&Bc[cur][wn * 32 + j * 16 + (lane & 15)][(lane >> 4) * 8];
    for (int i = 0; i < 4; ++i)
      for (int j = 0; j < 2; ++j)
        acc[i][j] = __builtin_amdgcn_mfma_f32_16x16x32_bf16(af[i], bc[j], acc[i][j], 0, 0, 0);
    if (ki < 7) {
      int nxt = cur ^ 1;
      *(int4*)&As[nxt][r][c] = rav;
      *(int4*)&Bc[nxt][r][c] = rb2;
      cur = nxt;
    }
    __syncthreads();
  }
  int p0 = tm * 128 + wm * 64, d0 = tn * 128 + wn * 32;
  for (int i = 0; i < 4; ++i)
    for (int rr = 0; rr < 4; ++rr) {
      int p = p0 + i * 16 + (lane >> 4) * 4 + rr;
      size_t rowo = ((size_t)b * PLEN + p) * DIM;
      for (int j = 0; j < 2; ++j) {
        int d = d0 + j * 16 + (lane & 15);
        out2[rowo + d] = acc[i][j][rr];
      }
    }
}

extern "C" void kernel_launch(void* const* d_in, const int* in_sizes, int n_in,
                              void* d_out, int out_size, void* d_ws, size_t ws_size,
                              hipStream_t stream) {
  const float* passage  = (const float*)d_in[0];
  const float* question = (const float*)d_in[1];
  const int*   pmask    = (const int*)d_in[2];
  const int*   qmask    = (const int*)d_in[3];
  const float* W        = (const float*)d_in[4];
  const float* bias     = (const float*)d_in[5];
  float* out = (float*)d_out;

  const size_t NS = (size_t)NB * PLEN * QLEN;    // 4,194,304
  const size_t NQ = (size_t)NB * QLEN * DIM;     // 1,048,576
  char* w = (char*)d_ws;
  unsigned short* Qb   = (unsigned short*)w; w += NQ * 2;
  unsigned short* PbT  = (unsigned short*)w; w += NS * 2;
  unsigned short* QbT  = (unsigned short*)w; w += NQ * 2;
  unsigned short* P2Q  = (unsigned short*)w; w += NS * 2;
  unsigned short* P2Qt = (unsigned short*)w; w += NS * 2;
  unsigned short* QATTt = (unsigned short*)w; w += NQ * 2;
  float* CM = (float*)w;                     w += (size_t)NB * 16 * QLEN * 4;
  float* CL = (float*)w;                     w += (size_t)NB * 16 * QLEN * 4;
  float* RM = (float*)w;                     w += (size_t)NB * PLEN * 4;
  float* RL = (float*)w;                     w += (size_t)NB * PLEN * 4;
  float* sq = (float*)w;

  float* out1 = out;
  float* out2 = out + (size_t)NB * PLEN * DIM;

  k_prepQ<<<dim3(NB * 4), dim3(256), 0, stream>>>(
      question, W, Qb, QbT, sq);
  k_scoreA<<<dim3(NB * 16), dim3(1024), 0, stream>>>(
      passage, Qb, W, sq, pmask, qmask, bias, PbT, CM, CL, RM, RL, P2Q, P2Qt);
  k_mid<<<dim3(NB * 32), dim3(512), 0, stream>>>(
      P2Qt, PbT, P2Q, QbT, RM, RL, CM, CL, QATTt, out1);
  k_final2<<<dim3(NB * 16), dim3(512), 0, stream>>>(
      P2Q, QATTt, out2);
}

// Round 15
// 58.618 us; speedup vs baseline: 1.5868x; 1.0500x over previous
//
#include <hip/hip_runtime.h>
#include <math.h>

#define NB 16
#define PLEN 1024
#define QLEN 256
#define DIM 256
#define MASKV -10000000.0f

typedef __attribute__((ext_vector_type(8))) short short8;
typedef __attribute__((ext_vector_type(4))) float f32x4;

union u4x16 { unsigned short u[4]; int2 v; };
union u8x16 { unsigned short u[8]; int4 v; };
union u16x16 { unsigned short u[16]; int4 v[2]; };

__device__ inline unsigned short f2bf(float x) {
  unsigned int u = __float_as_uint(x);
  u += 0x7FFF + ((u >> 16) & 1);          // round-to-nearest-even
  return (unsigned short)(u >> 16);
}
__device__ inline float bf2f(unsigned short u) {
  return __uint_as_float(((unsigned int)u) << 16);
}
__device__ inline int4 pack8(float4 a, float4 b) {
  u8x16 o;
  o.u[0] = f2bf(a.x); o.u[1] = f2bf(a.y); o.u[2] = f2bf(a.z); o.u[3] = f2bf(a.w);
  o.u[4] = f2bf(b.x); o.u[5] = f2bf(b.y); o.u[6] = f2bf(b.z); o.u[7] = f2bf(b.w);
  return o.v;
}

// ---------------- k_scoreA (grid NB*16, 1024 thr = 16 waves): 64 p-rows x 256 q.
// Inline passage prep + inline question staging (fp32->bf16) + inline sq rowdot
// + score GEMM + mask + col partials + exact row softmax -> P2Q, P2Qt, RM/RL, PbT.
// Blocks with tile<4 additionally emit their 64-row chunk of QbT.
__global__ __launch_bounds__(1024) void k_scoreA(
    const float* __restrict__ passage, const float* __restrict__ question,
    const float* __restrict__ Wg,
    const int* __restrict__ pmask, const int* __restrict__ qmask,
    const float* __restrict__ bias,
    unsigned short* __restrict__ PbT, unsigned short* __restrict__ QbT,
    float* __restrict__ CM, float* __restrict__ CL,
    float* __restrict__ RM, float* __restrict__ RL,
    unsigned short* __restrict__ P2Q, unsigned short* __restrict__ P2Qt) {
  int bid0 = blockIdx.x;
  int bid = (bid0 & 7) * 32 + (bid0 >> 3);           // XCD swizzle (256 = 8 * 32, bijective)
  int b = bid >> 4;
  int tile = bid & 15;
  int p0 = tile * 64;
  int t = threadIdx.x, lane = t & 63, wv = t >> 6;   // 16 waves
  int s = wv >> 2, h = wv & 3;
  __shared__ __align__(16) unsigned short As[2][64][40];
  __shared__ __align__(16) unsigned short Bs[2][256][40];
  __shared__ __align__(16) unsigned short Pl[64][264];
  __shared__ float redM[4][256], redL[4][256];
  __shared__ float rowM[64][4], rowL[64][4];
  __shared__ float spS[64];
  __shared__ float sqS[256];

  int rb = t >> 2, cb = (t & 3) * 8;     // Bs staging: row, col-chunk (8)
  int pr = t >> 4, pc = (t & 15) * 2;    // passage fp32 load: row, col-pair
  const float* psrc = passage + ((size_t)b * PLEN + p0 + pr) * DIM;
  const float* qsrc = question + ((size_t)b * QLEN + rb) * DIM;
  const float* wq = Wg + DIM;

  // ---- phase 1: inline-prep + score GEMM (64 x 256, K = 256), dbuf
  f32x4 acc[4] = {};
  float spp = 0.f, sqq = 0.f;
  float4 qa = *(const float4*)&qsrc[cb];
  float4 qb_ = *(const float4*)&qsrc[cb + 4];
  float2 xv = *(const float2*)(psrc + pc);
  {
    sqq += qa.x * wq[cb]     + qa.y * wq[cb + 1] + qa.z * wq[cb + 2] + qa.w * wq[cb + 3]
         + qb_.x * wq[cb + 4] + qb_.y * wq[cb + 5] + qb_.z * wq[cb + 6] + qb_.w * wq[cb + 7];
    *(int4*)&Bs[0][rb][cb] = pack8(qa, qb_);
    spp += xv.x * Wg[pc] + xv.y * Wg[pc + 1];
    unsigned int raw = (unsigned int)f2bf(xv.x) | (((unsigned int)f2bf(xv.y)) << 16);
    unsigned int wgt = (unsigned int)f2bf(xv.x * Wg[2 * DIM + pc])
                     | (((unsigned int)f2bf(xv.y * Wg[2 * DIM + pc + 1])) << 16);
    *(unsigned int*)&Pl[pr][pc] = raw;
    *(unsigned int*)&As[0][pr][pc] = wgt;
  }
  __syncthreads();
  int cur = 0;
  for (int ki = 0; ki < 8; ++ki) {
    float2 xn; float4 qa2, qb2;
    if (ki < 7) {
      int kt = (ki + 1) * 32;
      qa2 = *(const float4*)&qsrc[kt + cb];
      qb2 = *(const float4*)&qsrc[kt + cb + 4];
      xn = *(const float2*)(psrc + kt + pc);
    }
    short8 af = *(const short8*)&As[cur][s * 16 + (lane & 15)][(lane >> 4) * 8];
    for (int j = 0; j < 4; ++j) {
      short8 bf = *(const short8*)&Bs[cur][h * 64 + j * 16 + (lane & 15)][(lane >> 4) * 8];
      acc[j] = __builtin_amdgcn_mfma_f32_16x16x32_bf16(af, bf, acc[j], 0, 0, 0);
    }
    if (ki < 7) {
      int kt = (ki + 1) * 32;
      int dq = kt + cb, dp = kt + pc;
      sqq += qa2.x * wq[dq]     + qa2.y * wq[dq + 1] + qa2.z * wq[dq + 2] + qa2.w * wq[dq + 3]
           + qb2.x * wq[dq + 4] + qb2.y * wq[dq + 5] + qb2.z * wq[dq + 6] + qb2.w * wq[dq + 7];
      spp += xn.x * Wg[dp] + xn.y * Wg[dp + 1];
      unsigned int raw = (unsigned int)f2bf(xn.x) | (((unsigned int)f2bf(xn.y)) << 16);
      unsigned int wgt = (unsigned int)f2bf(xn.x * Wg[2 * DIM + dp])
                       | (((unsigned int)f2bf(xn.y * Wg[2 * DIM + dp + 1])) << 16);
      int nxt = cur ^ 1;
      *(unsigned int*)&Pl[pr][dp] = raw;
      *(unsigned int*)&As[nxt][pr][pc] = wgt;
      *(int4*)&Bs[nxt][rb][cb] = pack8(qa2, qb2);
      cur = nxt;
    }
    __syncthreads();
  }

  // ---- sq reduce (4 threads per question row) -> sqS
  sqq += __shfl_xor(sqq, 1, 64);
  sqq += __shfl_xor(sqq, 2, 64);
  if ((t & 3) == 0) sqS[rb] = sqq;
  // ---- sp reduce (16 threads per passage row) -> spS
  spp += __shfl_xor(spp, 1, 64);
  spp += __shfl_xor(spp, 2, 64);
  spp += __shfl_xor(spp, 4, 64);
  spp += __shfl_xor(spp, 8, 64);
  if ((t & 15) == 0) spS[pr] = spp;
  // ---- PbT transpose-out from Pl
  {
    int d = t >> 2, ch = t & 3;
    u16x16 o;
    for (int e = 0; e < 16; ++e) o.u[e] = Pl[ch * 16 + e][d];
    unsigned short* dst = PbT + ((size_t)b * DIM + d) * PLEN + p0 + ch * 16;
    *(int4*)dst = o.v[0];
    *(int4*)(dst + 8) = o.v[1];
  }
  __syncthreads();

  // ---- phase 2: bias + mask epilogue
  float b0 = bias[0];
  int prow[4]; float spv[4]; int pmv[4];
  for (int r = 0; r < 4; ++r) {
    int rl = s * 16 + (lane >> 4) * 4 + r;
    prow[r] = p0 + rl;
    spv[r] = spS[rl] + b0;
    pmv[r] = pmask[b * PLEN + prow[r]];
  }
  float sqv[4]; int qmv[4];
  for (int j = 0; j < 4; ++j) {
    int q = h * 64 + j * 16 + (lane & 15);
    sqv[j] = sqS[q];
    qmv[j] = qmask[b * QLEN + q];
  }
  for (int j = 0; j < 4; ++j)
    for (int r = 0; r < 4; ++r) {
      float v = acc[j][r] + spv[r] + sqv[j];
      if (pmv[r] | qmv[j]) v = MASKV;
      acc[j][r] = v;
    }

  // ---- phase 3a: column + row partials
  for (int j = 0; j < 4; ++j) {
    float m = fmaxf(fmaxf(acc[j][0], acc[j][1]), fmaxf(acc[j][2], acc[j][3]));
    m = fmaxf(m, __shfl_xor(m, 16, 64));
    m = fmaxf(m, __shfl_xor(m, 32, 64));
    float e = 0.f;
    for (int r = 0; r < 4; ++r) e += __expf(acc[j][r] - m);
    e += __shfl_xor(e, 16, 64);
    e += __shfl_xor(e, 32, 64);
    if ((lane >> 4) == 0) {
      redM[s][h * 64 + j * 16 + (lane & 15)] = m;
      redL[s][h * 64 + j * 16 + (lane & 15)] = e;
    }
  }
  for (int r = 0; r < 4; ++r) {
    int rl = s * 16 + (lane >> 4) * 4 + r;
    float m = acc[0][r];
    for (int j = 1; j < 4; ++j) m = fmaxf(m, acc[j][r]);
    for (int msk = 1; msk <= 8; msk <<= 1) m = fmaxf(m, __shfl_xor(m, msk, 64));
    float l = 0.f;
    for (int j = 0; j < 4; ++j) l += __expf(acc[j][r] - m);
    for (int msk = 1; msk <= 8; msk <<= 1) l += __shfl_xor(l, msk, 64);
    if ((lane & 15) == 0) { rowM[rl][h] = m; rowL[rl][h] = l; }
  }
  __syncthreads();

  // ---- phase 3b: CM/CL store
  if (t < 256) {
    int q = t;
    float M = fmaxf(fmaxf(redM[0][q], redM[1][q]), fmaxf(redM[2][q], redM[3][q]));
    float L = redL[0][q] * __expf(redM[0][q] - M) + redL[1][q] * __expf(redM[1][q] - M)
            + redL[2][q] * __expf(redM[2][q] - M) + redL[3][q] * __expf(redM[3][q] - M);
    size_t o = ((size_t)b * 16 + tile) * QLEN + q;
    CM[o] = M; CL[o] = L;
  }

  // ---- phase 4: exact row softmax -> Pl (bf16) + RM/RL
  for (int r = 0; r < 4; ++r) {
    int rl = s * 16 + (lane >> 4) * 4 + r;
    float m0 = rowM[rl][0], m1 = rowM[rl][1], m2 = rowM[rl][2], m3 = rowM[rl][3];
    float m = fmaxf(fmaxf(m0, m1), fmaxf(m2, m3));
    float l = rowL[rl][0] * __expf(m0 - m) + rowL[rl][1] * __expf(m1 - m)
            + rowL[rl][2] * __expf(m2 - m) + rowL[rl][3] * __expf(m3 - m);
    if (h == 0 && (lane & 15) == 0) {
      RM[(size_t)b * PLEN + p0 + rl] = m;
      RL[(size_t)b * PLEN + p0 + rl] = l;
    }
    float inv = 1.0f / l;
    for (int j = 0; j < 4; ++j) {
      float e = (pmv[r] | qmv[j]) ? 0.0f : __expf(acc[j][r] - m) * inv;
      Pl[rl][h * 64 + j * 16 + (lane & 15)] = f2bf(e);
    }
  }
  __syncthreads();

  // ---- P2Q row-major store
  for (int k = 0; k < 2; ++k) {
    int idx = t + k * 1024;
    int row = idx >> 5, c8 = idx & 31;
    *(int4*)&P2Q[((size_t)b * PLEN + p0 + row) * QLEN + c8 * 8] = *(const int4*)&Pl[row][c8 * 8];
  }
  // ---- P2Qt transposed store
  {
    int q = t >> 2, pcc = t & 3;
    u16x16 o;
    for (int e = 0; e < 16; ++e) o.u[e] = Pl[pcc * 16 + e][q];
    unsigned short* dst = P2Qt + ((size_t)b * QLEN + q) * PLEN + p0 + pcc * 16;
    *(int4*)dst = o.v[0];
    *(int4*)(dst + 8) = o.v[1];
  }

  // ---- QbT production (tile 0..3 only): 64 question rows -> QbT chunk
  if (tile < 4) {
    __syncthreads();             // Pl reads above complete before overwrite
    int r0 = tile * 64;
    const float* src = question + ((size_t)b * QLEN + r0) * DIM;
    int row = t >> 4, c0 = (t & 15) * 16;
    for (int i = 0; i < 4; ++i) {
      int d = c0 + i * 4;
      float4 x = *(const float4*)&src[(size_t)row * DIM + d];
      u4x16 tv;
      tv.u[0] = f2bf(x.x); tv.u[1] = f2bf(x.y); tv.u[2] = f2bf(x.z); tv.u[3] = f2bf(x.w);
      *(int2*)&Pl[row][d] = tv.v;
    }
    __syncthreads();
    for (int it = 0; it < 2; ++it) {
      int g = t + it * 1024;
      int d = g >> 3, ch = g & 7;
      u8x16 o;
      for (int e = 0; e < 8; ++e) o.u[e] = Pl[ch * 8 + e][d];
      *(int4*)&QbT[(size_t)(b * DIM + d) * QLEN + r0 + ch * 8] = o.v;
    }
  }
}

// ---------------- k_mid (512 thr, grid NB*32): heterogeneous overlap.
// Blocks [0, NB*16): fused col-softmax + qatt GEMM -> QATTt.
// Blocks [NB*16, NB*32): out1 = P2Q @ QbT^T (128p x 128d tiles).
__global__ __launch_bounds__(512) void k_mid(
    const unsigned short* __restrict__ P2Qt, const unsigned short* __restrict__ PbT,
    const unsigned short* __restrict__ P2Q, const unsigned short* __restrict__ QbT,
    const float* __restrict__ RM, const float* __restrict__ RL,
    const float* __restrict__ CM, const float* __restrict__ CL,
    unsigned short* __restrict__ QATTt, float* __restrict__ out1) {
  __shared__ __align__(16) char smem[40960];
  int t = threadIdx.x, lane = t & 63, wid = t >> 6;

  if (blockIdx.x < NB * 16) {
    // ======== qatt2 ========
    int bid = blockIdx.x;
    int b = bid >> 4, dt = (bid >> 2) & 3, qt = bid & 3;
    int wm = wid >> 2, wn = wid & 3;                 // wave = 32 d x 16 q
    typedef unsigned short row72[72];
    row72* Wt = (row72*)smem;
    row72* At = (row72*)(smem + 9216);
    float* MqS = (float*)(smem + 18432);
    float* iLqS = (float*)(smem + 18688);
    if (t < 64) {
      int q = qt * 64 + t;
      float M = CM[((size_t)b * 16) * QLEN + q];
      for (int tm = 1; tm < 16; ++tm)
        M = fmaxf(M, CM[((size_t)b * 16 + tm) * QLEN + q]);
      float L = 0.f;
      for (int tm = 0; tm < 16; ++tm) {
        size_t o = ((size_t)b * 16 + tm) * QLEN + q;
        L += CL[o] * __expf(CM[o] - M);
      }
      MqS[t] = (M < -1.0e6f) ? 1.0e30f : M;
      iLqS[t] = 1.0f / L;
    }
    __syncthreads();

    int rrow = t >> 3;
    int pch = (t & 7) * 8;
    const unsigned short* Wsrc = P2Qt + ((size_t)b * QLEN + qt * 64 + rrow) * PLEN + pch;
    const unsigned short* Asrc = PbT + ((size_t)b * DIM + dt * 64 + rrow) * PLEN + pch;
    const float* rmB = RM + (size_t)b * PLEN + pch;
    const float* rlB = RL + (size_t)b * PLEN + pch;
    float Mq = MqS[rrow], giL = iLqS[rrow];

    f32x4 acc[2] = {};
    int4 wvv = *(const int4*)Wsrc;
    int4 av = *(const int4*)Asrc;
    float4 rm0 = *(const float4*)rmB, rm1 = *(const float4*)(rmB + 4);
    float4 rl0 = *(const float4*)rlB, rl1 = *(const float4*)(rlB + 4);

    for (int ps = 0; ps < 16; ++ps) {
      float rmv[8] = {rm0.x, rm0.y, rm0.z, rm0.w, rm1.x, rm1.y, rm1.z, rm1.w};
      float rlv[8] = {rl0.x, rl0.y, rl0.z, rl0.w, rl1.x, rl1.y, rl1.z, rl1.w};
      const unsigned short* wu = (const unsigned short*)&wvv;
      u8x16 wo;
#pragma unroll
      for (int e = 0; e < 8; ++e) {
        float w = bf2f(wu[e]) * rlv[e] * __expf(rmv[e] - Mq) * giL;
        wo.u[e] = f2bf(w);
      }
      *(int4*)&Wt[rrow][pch] = wo.v;
      *(int4*)&At[rrow][pch] = av;
      if (ps < 15) {
        int off = (ps + 1) * 64;
        wvv = *(const int4*)(Wsrc + off);
        av = *(const int4*)(Asrc + off);
        rm0 = *(const float4*)(rmB + off); rm1 = *(const float4*)(rmB + off + 4);
        rl0 = *(const float4*)(rlB + off); rl1 = *(const float4*)(rlB + off + 4);
      }
      __syncthreads();
      for (int kk = 0; kk < 64; kk += 32) {
        short8 bf = *(const short8*)&Wt[wn * 16 + (lane & 15)][kk + (lane >> 4) * 8];
        for (int i = 0; i < 2; ++i) {
          short8 af = *(const short8*)&At[wm * 32 + i * 16 + (lane & 15)][kk + (lane >> 4) * 8];
          acc[i] = __builtin_amdgcn_mfma_f32_16x16x32_bf16(af, bf, acc[i], 0, 0, 0);
        }
      }
      __syncthreads();
    }
    int d0 = dt * 64 + wm * 32, q0 = qt * 64 + wn * 16;
    for (int i = 0; i < 2; ++i)
      for (int rr = 0; rr < 4; ++rr) {
        int d = d0 + i * 16 + (lane >> 4) * 4 + rr;
        QATTt[((size_t)b * DIM + d) * QLEN + q0 + (lane & 15)] = f2bf(acc[i][rr]);
      }
  } else {
    // ======== out1 = P2Q @ QbT^T ========
    int bid = blockIdx.x - NB * 16;
    int b = bid >> 4;
    int tm = (bid >> 1) & 7;
    int tn = bid & 1;
    const unsigned short* A  = P2Q + ((size_t)b * PLEN + tm * 128) * QLEN;
    const unsigned short* B1 = QbT + ((size_t)b * DIM + tn * 128) * QLEN;
    typedef unsigned short row40[40];
    row40* As2 = (row40*)smem;
    row40* Bq = (row40*)(smem + 20480);
    int wm = wid >> 2, wn = wid & 3;           // wave = 64 p x 32 d
    f32x4 acc1[4][2] = {};
    int r = t >> 2, c = (t & 3) * 8;
    int4 rav = *(const int4*)&A[(size_t)r * QLEN + c];
    int4 rb1 = *(const int4*)&B1[(size_t)r * QLEN + c];
    *(int4*)&As2[r][c] = rav;
    *(int4*)&Bq[r][c] = rb1;
    __syncthreads();
    int cur = 0;
    for (int ki = 0; ki < 8; ++ki) {
      if (ki < 7) {
        int kt = (ki + 1) * 32;
        rav = *(const int4*)&A[(size_t)r * QLEN + kt + c];
        rb1 = *(const int4*)&B1[(size_t)r * QLEN + kt + c];
      }
      short8 af[4], b1v[2];
      for (int i = 0; i < 4; ++i)
        af[i] = *(const short8*)&As2[cur * 128 + wm * 64 + i * 16 + (lane & 15)][(lane >> 4) * 8];
      for (int j = 0; j < 2; ++j)
        b1v[j] = *(const short8*)&Bq[cur * 128 + wn * 32 + j * 16 + (lane & 15)][(lane >> 4) * 8];
      for (int i = 0; i < 4; ++i)
        for (int j = 0; j < 2; ++j)
          acc1[i][j] = __builtin_amdgcn_mfma_f32_16x16x32_bf16(af[i], b1v[j], acc1[i][j], 0, 0, 0);
      if (ki < 7) {
        int nxt = cur ^ 1;
        *(int4*)&As2[nxt * 128 + r][c] = rav;
        *(int4*)&Bq[nxt * 128 + r][c] = rb1;
        cur = nxt;
      }
      __syncthreads();
    }
    int p0 = tm * 128 + wm * 64, d0 = tn * 128 + wn * 32;
    for (int i = 0; i < 4; ++i)
      for (int rr = 0; rr < 4; ++rr) {
        int p = p0 + i * 16 + (lane >> 4) * 4 + rr;
        size_t rowo = ((size_t)b * PLEN + p) * DIM;
        for (int j = 0; j < 2; ++j) {
          int d = d0 + j * 16 + (lane & 15);
          out1[rowo + d] = acc1[i][j][rr];
        }
      }
  }
}

// ---------------- k_final2 (512 thr): out2 = P2Q @ QATTt^T; 128p x 128d, dbuf
__global__ __launch_bounds__(512) void k_final2(
    const unsigned short* __restrict__ P2Q, const unsigned short* __restrict__ QATTt,
    float* __restrict__ out2) {
  int bid = blockIdx.x;
  int b = bid >> 4;
  int tm = (bid >> 1) & 7;
  int tn = bid & 1;
  const unsigned short* A  = P2Q + ((size_t)b * PLEN + tm * 128) * QLEN;
  const unsigned short* B2 = QATTt + ((size_t)b * DIM + tn * 128) * QLEN;
  __shared__ __align__(16) unsigned short As[2][128][40];
  __shared__ __align__(16) unsigned short Bc[2][128][40];
  int t = threadIdx.x, lane = t & 63, wid = t >> 6;
  int wm = wid >> 2, wn = wid & 3;       // wave = 64 p x 32 d
  f32x4 acc[4][2] = {};
  int r = t >> 2, c = (t & 3) * 8;
  int4 rav = *(const int4*)&A[(size_t)r * QLEN + c];
  int4 rb2 = *(const int4*)&B2[(size_t)r * QLEN + c];
  *(int4*)&As[0][r][c] = rav;
  *(int4*)&Bc[0][r][c] = rb2;
  __syncthreads();
  int cur = 0;
  for (int ki = 0; ki < 8; ++ki) {
    if (ki < 7) {
      int kt = (ki + 1) * 32;
      rav = *(const int4*)&A[(size_t)r * QLEN + kt + c];
      rb2 = *(const int4*)&B2[(size_t)r * QLEN + kt + c];
    }
    short8 af[4], bc[2];
    for (int i = 0; i < 4; ++i)
      af[i] = *(const short8*)&As[cur][wm * 64 + i * 16 + (lane & 15)][(lane >> 4) * 8];
    for (int j = 0; j < 2; ++j)
      bc[j] = *(const short8*)&Bc[cur][wn * 32 + j * 16 + (lane & 15)][(lane >> 4) * 8];
    for (int i = 0; i < 4; ++i)
      for (int j = 0; j < 2; ++j)
        acc[i][j] = __builtin_amdgcn_mfma_f32_16x16x32_bf16(af[i], bc[j], acc[i][j], 0, 0, 0);
    if (ki < 7) {
      int nxt = cur ^ 1;
      *(int4*)&As[nxt][r][c] = rav;
      *(int4*)&Bc[nxt][r][c] = rb2;
      cur = nxt;
    }
    __syncthreads();
  }
  int p0 = tm * 128 + wm * 64, d0 = tn * 128 + wn * 32;
  for (int i = 0; i < 4; ++i)
    for (int rr = 0; rr < 4; ++rr) {
      int p = p0 + i * 16 + (lane >> 4) * 4 + rr;
      size_t rowo = ((size_t)b * PLEN + p) * DIM;
      for (int j = 0; j < 2; ++j) {
        int d = d0 + j * 16 + (lane & 15);
        out2[rowo + d] = acc[i][j][rr];
      }
    }
}

extern "C" void kernel_launch(void* const* d_in, const int* in_sizes, int n_in,
                              void* d_out, int out_size, void* d_ws, size_t ws_size,
                              hipStream_t stream) {
  const float* passage  = (const float*)d_in[0];
  const float* question = (const float*)d_in[1];
  const int*   pmask    = (const int*)d_in[2];
  const int*   qmask    = (const int*)d_in[3];
  const float* W        = (const float*)d_in[4];
  const float* bias     = (const float*)d_in[5];
  float* out = (float*)d_out;

  const size_t NS = (size_t)NB * PLEN * QLEN;    // 4,194,304
  const size_t NQ = (size_t)NB * QLEN * DIM;     // 1,048,576
  char* w = (char*)d_ws;
  unsigned short* PbT  = (unsigned short*)w; w += NS * 2;
  unsigned short* QbT  = (unsigned short*)w; w += NQ * 2;
  unsigned short* P2Q  = (unsigned short*)w; w += NS * 2;
  unsigned short* P2Qt = (unsigned short*)w; w += NS * 2;
  unsigned short* QATTt = (unsigned short*)w; w += NQ * 2;
  float* CM = (float*)w;                     w += (size_t)NB * 16 * QLEN * 4;
  float* CL = (float*)w;                     w += (size_t)NB * 16 * QLEN * 4;
  float* RM = (float*)w;                     w += (size_t)NB * PLEN * 4;
  float* RL = (float*)w;

  float* out1 = out;
  float* out2 = out + (size_t)NB * PLEN * DIM;

  k_scoreA<<<dim3(NB * 16), dim3(1024), 0, stream>>>(
      passage, question, W, pmask, qmask, bias, PbT, QbT, CM, CL, RM, RL, P2Q, P2Qt);
  k_mid<<<dim3(NB * 32), dim3(512), 0, stream>>>(
      P2Qt, PbT, P2Q, QbT, RM, RL, CM, CL, QATTt, out1);
  k_final2<<<dim3(NB * 16), dim3(512), 0, stream>>>(
      P2Q, QATTt, out2);
}